// Round 5
// baseline (293.416 us; speedup 1.0000x reference)
//
#include <hip/hip_runtime.h>

// ---------------- types ----------------
typedef __bf16 bf16x8 __attribute__((ext_vector_type(8)));
typedef float  f32x4  __attribute__((ext_vector_type(4)));

static __device__ __forceinline__ ushort f2bf(float f) {
    union { float f; unsigned u; } a; a.f = f;
    unsigned r = a.u + 0x7FFFu + ((a.u >> 16) & 1u);   // RNE
    return (ushort)(r >> 16);
}

// ---------------- constants ----------------
#define TS  2048   // S
#define TD  1024   // D
#define TL  256    // L
#define TH  1024   // H
#define TNH 16
#define THD 64
#define TDF 4096   // 4*D

// LDS swizzle helpers for 128-byte-row tiles (attn).
// lo: XOR in (row&7)   -> use when the WRITE pattern varies row within 8-blocks
// hi: XOR in (row>>3)  -> use when the write pattern varies row across 8-blocks
static __device__ __forceinline__ ushort* swzp_hi(ushort* base, int row, int colbyte) {
    return (ushort*)((char*)base + row * 128 + (colbyte ^ (((row >> 3) & 7) << 4)));
}
static __device__ __forceinline__ const ushort* swzp_hi(const ushort* base, int row, int colbyte) {
    return (const ushort*)((const char*)base + row * 128 + (colbyte ^ (((row >> 3) & 7) << 4)));
}
static __device__ __forceinline__ ushort* swzp_lo(ushort* base, int row, int colbyte) {
    return (ushort*)((char*)base + row * 128 + (colbyte ^ ((row & 7) << 4)));
}
static __device__ __forceinline__ const ushort* swzp_lo(const ushort* base, int row, int colbyte) {
    return (const ushort*)((const char*)base + row * 128 + (colbyte ^ ((row & 7) << 4)));
}

#define GLD_LDS(gp, lp) \
    __builtin_amdgcn_global_load_lds( \
        (const __attribute__((address_space(1))) unsigned int*)(gp), \
        (__attribute__((address_space(3))) unsigned int*)(lp), 16, 0, 0)

#define WAITV(N) asm volatile("s_waitcnt vmcnt(" #N ")" ::: "memory")

// ---------------- weight transpose + f32->bf16 ----------------
__global__ __launch_bounds__(256) void transpose_to_bf16(
    const float* __restrict__ in, ushort* __restrict__ out, int K, int N)
{
    __shared__ float tile[32][33];
    const int k0 = blockIdx.x * 32, n0 = blockIdx.y * 32;
    const int tx = threadIdx.x, ty = threadIdx.y;   // block (32,8)
#pragma unroll
    for (int i = ty; i < 32; i += 8)
        tile[i][tx] = in[(size_t)(k0 + i) * N + n0 + tx];
    __syncthreads();
#pragma unroll
    for (int i = ty; i < 32; i += 8)
        out[(size_t)(n0 + i) * K + k0 + tx] = f2bf(tile[tx][i]);
}

// ---------------- small: concat two bias vectors ----------------
__global__ __launch_bounds__(256) void concat_bias_kernel(
    const float* __restrict__ a, const float* __restrict__ b,
    float* __restrict__ o, int n)
{
    const int i = blockIdx.x * 256 + threadIdx.x;
    o[i] = (i < n) ? a[i] : b[i - n];
}

// ---------------- RMSNorm: f32 in -> bf16 out ----------------
__global__ __launch_bounds__(256) void rmsnorm_kernel(
    const float* __restrict__ x, const float* __restrict__ g,
    ushort* __restrict__ out, int D)
{
    const int row = blockIdx.x;
    const int tid = threadIdx.x;
    const float4 v = ((const float4*)(x + (size_t)row * D))[tid];
    float ss = v.x * v.x + v.y * v.y + v.z * v.z + v.w * v.w;
#pragma unroll
    for (int off = 32; off > 0; off >>= 1) ss += __shfl_down(ss, off);
    __shared__ float sums[4];
    if ((tid & 63) == 0) sums[tid >> 6] = ss;
    __syncthreads();
    const float tot = sums[0] + sums[1] + sums[2] + sums[3];
    const float scale = rsqrtf(tot / (float)D + 1e-6f);
    const float4 gv = ((const float4*)g)[tid];
    ushort4 o;
    o.x = f2bf(v.x * scale * gv.x);
    o.y = f2bf(v.y * scale * gv.y);
    o.z = f2bf(v.z * scale * gv.z);
    o.w = f2bf(v.w * scale * gv.w);
    *(ushort4*)(out + (size_t)row * D + tid * 4) = o;
}

// ---------------- bf16 GEMM: C = A @ BT^T + bias, epilogue -------------------
// 3-deep ring-buffered LDS with COUNTED vmcnt (T4: never drain to 0 in loop).
// Per step t: wait own stage(t) (vmcnt LPS), barrier, issue stage(t+2), compute.
// 256 threads, 2x2 wave grid. EPI: 0=bf16; 1=silu->bf16; 2=+resid->f32; 3=silu+resid->f32
template <int EPI, int BM, int BN>
__global__ __launch_bounds__(256) void gemm_bf16_kernel(
    const ushort* __restrict__ A, const ushort* __restrict__ BT,
    const float* __restrict__ bias, const float* __restrict__ resid,
    void* __restrict__ outp, int M, int N, int K)
{
    constexpr int BK = 32;
    constexpr int WM = BM / 2, WN = BN / 2;
    constexpr int MT = WM / 16, NT = WN / 16;
    constexpr int NLA = BM / 64, NLB = BN / 64;   // gload_lds lines per matrix
    constexpr int LPS = NLA + NLB;                // loads per stage (per wave)
    __shared__ alignas(16) ushort As[3][BM * BK];
    __shared__ alignas(16) ushort Bs[3][BN * BK];
    const int bm = blockIdx.y * BM, bn = blockIdx.x * BN;
    const int tid = threadIdx.x;
    const int lane = tid & 63, wave = tid >> 6;
    const int wr = (wave >> 1) * WM, wc = (wave & 1) * WN;
    const int l15 = lane & 15, l4 = lane >> 4;

    f32x4 acc[MT][NT] = {};

    // one gload_lds line: 4 waves x 64 lanes x 16B = 64 rows x 32 cols (bf16)
    const int grow = wave * 16 + (lane >> 2);
    const int gcol = (lane & 3) * 8;
    const ushort* Ag = A + (size_t)(bm + grow) * K + gcol;
    const ushort* Bg = BT + (size_t)(bn + grow) * K + gcol;

    auto stage = [&](int buf, int k0) {
#pragma unroll
        for (int i = 0; i < NLA; ++i)
            GLD_LDS(Ag + (size_t)(i * 64) * K + k0, &As[buf][(i * 64 + wave * 16) * BK]);
#pragma unroll
        for (int i = 0; i < NLB; ++i)
            GLD_LDS(Bg + (size_t)(i * 64) * K + k0, &Bs[buf][(i * 64 + wave * 16) * BK]);
    };

    const int nsteps = K / BK;
    stage(0, 0);
    stage(1, BK);

    for (int t = 0; t < nsteps; ++t) {
        const int cur = t % 3;
        if (t + 1 < nsteps) {
            if constexpr (LPS == 2)      WAITV(2);
            else if constexpr (LPS == 3) WAITV(3);
            else                         WAITV(4);
        } else {
            WAITV(0);
        }
        __builtin_amdgcn_s_barrier();
        asm volatile("" ::: "memory");   // keep LDS reads below the barrier
        if (t + 2 < nsteps) stage((t + 2) % 3, (t + 2) * BK);

        bf16x8 af[MT], bf[NT];
#pragma unroll
        for (int mt = 0; mt < MT; ++mt)
            af[mt] = *(const bf16x8*)&As[cur][(wr + mt * 16 + l15) * BK + l4 * 8];
#pragma unroll
        for (int nt = 0; nt < NT; ++nt)
            bf[nt] = *(const bf16x8*)&Bs[cur][(wc + nt * 16 + l15) * BK + l4 * 8];
#pragma unroll
        for (int mt = 0; mt < MT; ++mt)
#pragma unroll
            for (int nt = 0; nt < NT; ++nt)
                acc[mt][nt] = __builtin_amdgcn_mfma_f32_16x16x32_bf16(
                    af[mt], bf[nt], acc[mt][nt], 0, 0, 0);
    }

#pragma unroll
    for (int mt = 0; mt < MT; ++mt) {
#pragma unroll
        for (int nt = 0; nt < NT; ++nt) {
#pragma unroll
            for (int i = 0; i < 4; ++i) {
                const int row = bm + wr + mt * 16 + l4 * 4 + i;
                const int col = bn + wc + nt * 16 + l15;
                float v = acc[mt][nt][i] + bias[col];
                if constexpr (EPI == 1 || EPI == 3) v = v / (1.f + __expf(-v));  // silu
                if constexpr (EPI == 2 || EPI == 3) v += resid[(size_t)row * N + col];
                if constexpr (EPI == 0 || EPI == 1)
                    ((ushort*)outp)[(size_t)row * N + col] = f2bf(v);
                else
                    ((float*)outp)[(size_t)row * N + col] = v;
            }
        }
    }
}

// ---------------- causal flash attention (MLA), 16 heads, HD=64 ----------------
// grid (32, 16); block 512 = 8 waves. Split-KV: group g = wave>>2 handles
// kv-tiles kt == g (mod 2); flash-combine of the two partials at the end.
// Q,O stride 1024; K,V live in fused kvbuf, stride 2048 (V = base + 1024).
__global__ __launch_bounds__(512) void mla_attn_kernel(
    const ushort* __restrict__ Q, const ushort* __restrict__ Kg,
    const ushort* __restrict__ Vg, ushort* __restrict__ O)
{
    constexpr int QSTR = 1024, KSTR = 2048;
    __shared__ alignas(16) ushort Ks[2][64 * 64];    // [g][key][d], lo-swizzled
    __shared__ alignas(16) ushort VTs[2][64 * 64];   // [g][d][key], hi-swizzled
    __shared__ alignas(16) ushort Ps[8][16 * 64];    // per-wave [row][key], lo-swizzled
    __shared__ float mlm[4][16], mll[4][16];
    const int qb = (int)gridDim.x - 1 - (int)blockIdx.x;
    const int h = blockIdx.y;
    const int tid = threadIdx.x, lane = tid & 63, wave = tid >> 6;
    const int g = wave >> 2, ws = wave & 3;
    const int l15 = lane & 15, l4 = lane >> 4;
    const int qrow0 = qb * 64 + ws * 16;

    bf16x8 qf[2];
#pragma unroll
    for (int ks = 0; ks < 2; ++ks)
        qf[ks] = *(const bf16x8*)&Q[(size_t)(qrow0 + l15) * QSTR + h * THD + ks * 32 + l4 * 8];

    f32x4 oacc[4] = {};
    float m_run[4], l_run[4];
#pragma unroll
    for (int i = 0; i < 4; ++i) { m_run[i] = -1e30f; l_run[i] = 0.f; }

    // group-local staging coords (256 threads cover 32 rows x 64 cols, 2 rows/thread)
    const int gt = ws * 64 + lane;
    const int sr = gt >> 3, sc = (gt & 7) * 8;
    const ushort* kbase = Kg + (size_t)sr * KSTR + h * THD + sc;
    const ushort* vbase = Vg + (size_t)sr * KSTR + h * THD + sc;

    uint4 kr0, kr1, vr0, vr1;
    if (g <= qb) {   // prefetch this group's first tile (kt = g)
        const size_t off = (size_t)g * 64 * KSTR;
        kr0 = *(const uint4*)(kbase + off);
        kr1 = *(const uint4*)(kbase + off + (size_t)32 * KSTR);
        vr0 = *(const uint4*)(vbase + off);
        vr1 = *(const uint4*)(vbase + off + (size_t)32 * KSTR);
    }

    const int maxiter = qb / 2 + 1;
    for (int j = 0; j < maxiter; ++j) {
        const int kt = 2 * j + g;
        const bool active = (kt <= qb);
        __syncthreads();   // everyone done reading buf[g] from prev iter
        if (active) {
            *(uint4*)swzp_lo(&Ks[g][0], sr, sc * 2) = kr0;
            *(uint4*)swzp_lo(&Ks[g][0], sr + 32, sc * 2) = kr1;
            const ushort* p0 = (const ushort*)&vr0;
            const ushort* p1 = (const ushort*)&vr1;
#pragma unroll
            for (int jj = 0; jj < 8; ++jj) {
                *swzp_hi(&VTs[g][0], sc + jj, sr * 2) = p0[jj];
                *swzp_hi(&VTs[g][0], sc + jj, (sr + 32) * 2) = p1[jj];
            }
        }
        __syncthreads();
        if (active && kt + 2 <= qb) {   // prefetch this group's next tile
            const size_t off = (size_t)(kt + 2) * 64 * KSTR;
            kr0 = *(const uint4*)(kbase + off);
            kr1 = *(const uint4*)(kbase + off + (size_t)32 * KSTR);
            vr0 = *(const uint4*)(vbase + off);
            vr1 = *(const uint4*)(vbase + off + (size_t)32 * KSTR);
        }
        if (!active) continue;

        // ---- scores: s[nt] = Q @ K^T ----
        f32x4 s[4] = {};
        __builtin_amdgcn_s_setprio(1);
#pragma unroll
        for (int ks = 0; ks < 2; ++ks) {
#pragma unroll
            for (int nt = 0; nt < 4; ++nt) {
                const bf16x8 kf = *(const bf16x8*)swzp_lo(&Ks[g][0], nt * 16 + l15, ks * 64 + l4 * 16);
                s[nt] = __builtin_amdgcn_mfma_f32_16x16x32_bf16(qf[ks], kf, s[nt], 0, 0, 0);
            }
        }
        __builtin_amdgcn_s_setprio(0);

        const int kb = kt * 64;
        const bool diag = (kt == qb);
#pragma unroll
        for (int i = 0; i < 4; ++i) {
            const int qrow = qrow0 + l4 * 4 + i;
            float mx = m_run[i];
#pragma unroll
            for (int nt = 0; nt < 4; ++nt) {
                float v = s[nt][i] * 0.125f;
                if (diag && (kb + nt * 16 + l15 > qrow)) v = -1e30f;
                s[nt][i] = v;
                mx = fmaxf(mx, v);
            }
#pragma unroll
            for (int d = 1; d < 16; d <<= 1) mx = fmaxf(mx, __shfl_xor(mx, d));
            const float alpha = __expf(m_run[i] - mx);
            l_run[i] *= alpha;
#pragma unroll
            for (int nt = 0; nt < 4; ++nt) oacc[nt][i] *= alpha;
            float ps = 0.f;
#pragma unroll
            for (int nt = 0; nt < 4; ++nt) {
                const float p = __expf(s[nt][i] - mx);
                s[nt][i] = p;
                ps += p;
            }
#pragma unroll
            for (int d = 1; d < 16; d <<= 1) ps += __shfl_xor(ps, d);
            l_run[i] += ps;
            m_run[i] = mx;
#pragma unroll
            for (int nt = 0; nt < 4; ++nt)
                *swzp_lo(&Ps[wave][0], l4 * 4 + i, (nt * 16 + l15) * 2) = f2bf(s[nt][i]);
        }

        // ---- PV ----
        __builtin_amdgcn_s_setprio(1);
#pragma unroll
        for (int ks = 0; ks < 2; ++ks) {
            const bf16x8 pf = *(const bf16x8*)swzp_lo(&Ps[wave][0], l15, ks * 64 + l4 * 16);
#pragma unroll
            for (int dt = 0; dt < 4; ++dt) {
                const bf16x8 vf = *(const bf16x8*)swzp_hi(&VTs[g][0], dt * 16 + l15, ks * 64 + l4 * 16);
                oacc[dt] = __builtin_amdgcn_mfma_f32_16x16x32_bf16(pf, vf, oacc[dt], 0, 0, 0);
            }
        }
        __builtin_amdgcn_s_setprio(0);
    }

    // ---- flash combine of the two groups' partials (reuse Ps as f32 buffer) ----
    // BARRIER FIRST: g0's final PV reads of Ps[0..3] must complete before g1
    // overwrites the Ps region with f32 partials (round-4 race fix).
    __syncthreads();
    if (g == 1) {
        float* cp = (float*)&Ps[0][0] + ws * 1024;
#pragma unroll
        for (int dt = 0; dt < 4; ++dt)
#pragma unroll
            for (int i = 0; i < 4; ++i)
                cp[(l4 * 4 + i) * 64 + dt * 16 + l15] = oacc[dt][i];
        if (l15 == 0) {
#pragma unroll
            for (int i = 0; i < 4; ++i) {
                mlm[ws][l4 * 4 + i] = m_run[i];
                mll[ws][l4 * 4 + i] = l_run[i];
            }
        }
    }
    __syncthreads();
    if (g == 0) {
        const float* cp = (const float*)&Ps[0][0] + ws * 1024;
#pragma unroll
        for (int i = 0; i < 4; ++i) {
            const int r16 = l4 * 4 + i;
            const float m1 = mlm[ws][r16], l1 = mll[ws][r16];
            const float m = fmaxf(m_run[i], m1);
            const float a0 = __expf(m_run[i] - m), a1 = __expf(m1 - m);
            const float inv = 1.f / (l_run[i] * a0 + l1 * a1);
            const int qrow = qrow0 + r16;
#pragma unroll
            for (int dt = 0; dt < 4; ++dt) {
                const float v = (oacc[dt][i] * a0 + cp[r16 * 64 + dt * 16 + l15] * a1) * inv;
                O[(size_t)qrow * QSTR + h * THD + dt * 16 + l15] = f2bf(v);
            }
        }
    }
}

// ---------------- launch ----------------
extern "C" void kernel_launch(void* const* d_in, const int* in_sizes, int n_in,
                              void* d_out, int out_size, void* d_ws, size_t ws_size,
                              hipStream_t stream)
{
    const float* x     = (const float*)d_in[0];
    const float* g1    = (const float*)d_in[1];
    const float* Wq    = (const float*)d_in[2];
    const float* bq    = (const float*)d_in[3];
    const float* Wdown = (const float*)d_in[4];
    const float* bdown = (const float*)d_in[5];
    const float* Wk    = (const float*)d_in[6];
    const float* bk    = (const float*)d_in[7];
    const float* Wv    = (const float*)d_in[8];
    const float* bv    = (const float*)d_in[9];
    const float* Wo    = (const float*)d_in[10];
    const float* bo    = (const float*)d_in[11];
    const float* g2    = (const float*)d_in[12];
    const float* W1    = (const float*)d_in[13];
    const float* b1    = (const float*)d_in[14];
    const float* W2    = (const float*)d_in[15];
    const float* b2    = (const float*)d_in[16];
    float* out = (float*)d_out;

    char* ws = (char*)d_ws;
    size_t off = 0;
    auto alloc = [&](size_t bytes) {
        void* p = ws + off;
        off += (bytes + 255) & ~(size_t)255;
        return p;
    };
    ushort* WqT    = (ushort*)alloc((size_t)TH * TD * 2);
    ushort* WdownT = (ushort*)alloc((size_t)TL * TD * 2);
    ushort* WkvT   = (ushort*)alloc((size_t)2 * TH * TL * 2);  // [2048][256]
    ushort* WoT    = (ushort*)alloc((size_t)TD * TH * 2);
    ushort* W1T    = (ushort*)alloc((size_t)TDF * TD * 2);
    ushort* W2T    = (ushort*)alloc((size_t)TD * TDF * 2);
    float*  bkv    = (float*)alloc((size_t)2 * TH * 4);
    ushort* hbuf   = (ushort*)alloc((size_t)TS * TD * 2);
    ushort* cbuf   = (ushort*)alloc((size_t)TS * TL * 2);
    ushort* qbuf   = (ushort*)alloc((size_t)TS * TH * 2);
    ushort* kvbuf  = (ushort*)alloc((size_t)TS * 2 * TH * 2);  // [S][2048]
    ushort* obuf   = (ushort*)alloc((size_t)TS * TH * 2);
    float*  strm   = (float*)alloc((size_t)TS * TD * 4);
    ushort* h2buf  = (ushort*)alloc((size_t)TS * TD * 2);
    ushort* ffn1   = (ushort*)alloc((size_t)TS * TDF * 2);

    const dim3 tb(32, 8);
    transpose_to_bf16<<<dim3(TD / 32, TH / 32), tb, 0, stream>>>(Wq, WqT, TD, TH);
    transpose_to_bf16<<<dim3(TD / 32, TL / 32), tb, 0, stream>>>(Wdown, WdownT, TD, TL);
    transpose_to_bf16<<<dim3(TL / 32, TH / 32), tb, 0, stream>>>(Wk, WkvT, TL, TH);
    transpose_to_bf16<<<dim3(TL / 32, TH / 32), tb, 0, stream>>>(Wv, WkvT + (size_t)TH * TL, TL, TH);
    transpose_to_bf16<<<dim3(TH / 32, TD / 32), tb, 0, stream>>>(Wo, WoT, TH, TD);
    transpose_to_bf16<<<dim3(TD / 32, TDF / 32), tb, 0, stream>>>(W1, W1T, TD, TDF);
    transpose_to_bf16<<<dim3(TDF / 32, TD / 32), tb, 0, stream>>>(W2, W2T, TDF, TD);
    concat_bias_kernel<<<(2 * TH) / 256, 256, 0, stream>>>(bk, bv, bkv, TH);

    rmsnorm_kernel<<<TS, 256, 0, stream>>>(x, g1, hbuf, TD);

    gemm_bf16_kernel<0, 128, 64><<<dim3(TH / 64, TS / 128), 256, 0, stream>>>(
        hbuf, WqT, bq, nullptr, qbuf, TS, TH, TD);
    gemm_bf16_kernel<0, 64, 64><<<dim3(TL / 64, TS / 64), 256, 0, stream>>>(
        hbuf, WdownT, bdown, nullptr, cbuf, TS, TL, TD);
    gemm_bf16_kernel<0, 128, 128><<<dim3(2 * TH / 128, TS / 128), 256, 0, stream>>>(
        cbuf, WkvT, bkv, nullptr, kvbuf, TS, 2 * TH, TL);

    mla_attn_kernel<<<dim3(TS / 64, TNH), 512, 0, stream>>>(
        qbuf, kvbuf, kvbuf + TH, obuf);

    gemm_bf16_kernel<2, 128, 64><<<dim3(TD / 64, TS / 128), 256, 0, stream>>>(
        obuf, WoT, bo, x, strm, TS, TD, TH);

    rmsnorm_kernel<<<TS, 256, 0, stream>>>(strm, g2, h2buf, TD);

    gemm_bf16_kernel<1, 128, 128><<<dim3(TDF / 128, TS / 128), 256, 0, stream>>>(
        h2buf, W1T, b1, nullptr, ffn1, TS, TDF, TD);
    gemm_bf16_kernel<3, 128, 64><<<dim3(TD / 64, TS / 128), 256, 0, stream>>>(
        ffn1, W2T, b2, strm, out, TS, TD, TDF);
}

// Round 6
// 267.108 us; speedup vs baseline: 1.0985x; 1.0985x over previous
//
#include <hip/hip_runtime.h>

// ---------------- types ----------------
typedef __bf16 bf16x8 __attribute__((ext_vector_type(8)));
typedef float  f32x4  __attribute__((ext_vector_type(4)));

static __device__ __forceinline__ ushort f2bf(float f) {
    union { float f; unsigned u; } a; a.f = f;
    unsigned r = a.u + 0x7FFFu + ((a.u >> 16) & 1u);   // RNE
    return (ushort)(r >> 16);
}

// ---------------- constants ----------------
#define TS  2048   // S
#define TD  1024   // D
#define TL  256    // L
#define TH  1024   // H
#define TNH 16
#define THD 64
#define TDF 4096   // 4*D

#define GLD_LDS(gp, lp) \
    __builtin_amdgcn_global_load_lds( \
        (const __attribute__((address_space(1))) unsigned int*)(gp), \
        (__attribute__((address_space(3))) unsigned int*)(lp), 16, 0, 0)

// ---------------- weight transpose + f32->bf16 ----------------
__global__ __launch_bounds__(256) void transpose_to_bf16(
    const float* __restrict__ in, ushort* __restrict__ out, int K, int N)
{
    __shared__ float tile[32][33];
    const int k0 = blockIdx.x * 32, n0 = blockIdx.y * 32;
    const int tx = threadIdx.x, ty = threadIdx.y;   // block (32,8)
#pragma unroll
    for (int i = ty; i < 32; i += 8)
        tile[i][tx] = in[(size_t)(k0 + i) * N + n0 + tx];
    __syncthreads();
#pragma unroll
    for (int i = ty; i < 32; i += 8)
        out[(size_t)(n0 + i) * K + k0 + tx] = f2bf(tile[tx][i]);
}

// ---------------- small: concat two bias vectors ----------------
__global__ __launch_bounds__(256) void concat_bias_kernel(
    const float* __restrict__ a, const float* __restrict__ b,
    float* __restrict__ o, int n)
{
    const int i = blockIdx.x * 256 + threadIdx.x;
    o[i] = (i < n) ? a[i] : b[i - n];
}

// ---------------- RMSNorm: f32 in -> bf16 out ----------------
__global__ __launch_bounds__(256) void rmsnorm_kernel(
    const float* __restrict__ x, const float* __restrict__ g,
    ushort* __restrict__ out, int D)
{
    const int row = blockIdx.x;
    const int tid = threadIdx.x;
    const float4 v = ((const float4*)(x + (size_t)row * D))[tid];
    float ss = v.x * v.x + v.y * v.y + v.z * v.z + v.w * v.w;
#pragma unroll
    for (int off = 32; off > 0; off >>= 1) ss += __shfl_down(ss, off);
    __shared__ float sums[4];
    if ((tid & 63) == 0) sums[tid >> 6] = ss;
    __syncthreads();
    const float tot = sums[0] + sums[1] + sums[2] + sums[3];
    const float scale = rsqrtf(tot / (float)D + 1e-6f);
    const float4 gv = ((const float4*)g)[tid];
    ushort4 o;
    o.x = f2bf(v.x * scale * gv.x);
    o.y = f2bf(v.y * scale * gv.y);
    o.z = f2bf(v.z * scale * gv.z);
    o.w = f2bf(v.w * scale * gv.w);
    *(ushort4*)(out + (size_t)row * D + tid * 4) = o;
}

// ---------------- bf16 GEMM (round-3 proven): C = A @ BT^T + bias -----------
// 2-phase double-buffered LDS, global_load_lds(16B), one vmcnt(0)+barrier/step.
// EPI: 0=bf16; 1=silu->bf16; 2=+resid->f32; 3=silu+resid->f32
template <int EPI, int BM, int BN>
__global__ __launch_bounds__(256) void gemm_bf16_kernel(
    const ushort* __restrict__ A, const ushort* __restrict__ BT,
    const float* __restrict__ bias, const float* __restrict__ resid,
    void* __restrict__ outp, int M, int N, int K)
{
    constexpr int BK = 32;
    constexpr int WM = BM / 2, WN = BN / 2;
    constexpr int MT = WM / 16, NT = WN / 16;
    constexpr int NLA = BM / 64, NLB = BN / 64;
    __shared__ alignas(16) ushort As[2][BM * BK];
    __shared__ alignas(16) ushort Bs[2][BN * BK];
    const int bm = blockIdx.y * BM, bn = blockIdx.x * BN;
    const int tid = threadIdx.x;
    const int lane = tid & 63, wave = tid >> 6;
    const int wr = (wave >> 1) * WM, wc = (wave & 1) * WN;
    const int l15 = lane & 15, l4 = lane >> 4;

    f32x4 acc[MT][NT] = {};

    const int grow = wave * 16 + (lane >> 2);
    const int gcol = (lane & 3) * 8;
    const ushort* Ag = A + (size_t)(bm + grow) * K + gcol;
    const ushort* Bg = BT + (size_t)(bn + grow) * K + gcol;

    auto stage = [&](int buf, int k0) {
#pragma unroll
        for (int i = 0; i < NLA; ++i)
            GLD_LDS(Ag + (size_t)(i * 64) * K + k0, &As[buf][(i * 64 + wave * 16) * BK]);
#pragma unroll
        for (int i = 0; i < NLB; ++i)
            GLD_LDS(Bg + (size_t)(i * 64) * K + k0, &Bs[buf][(i * 64 + wave * 16) * BK]);
    };

    stage(0, 0);
    asm volatile("s_waitcnt vmcnt(0)" ::: "memory");
    __syncthreads();

    const int nsteps = K / BK;
    for (int t = 0; t < nsteps; ++t) {
        const int cur = t & 1;
        if (t + 1 < nsteps) stage(cur ^ 1, (t + 1) * BK);

        bf16x8 af[MT], bf[NT];
#pragma unroll
        for (int mt = 0; mt < MT; ++mt)
            af[mt] = *(const bf16x8*)&As[cur][(wr + mt * 16 + l15) * BK + l4 * 8];
#pragma unroll
        for (int nt = 0; nt < NT; ++nt)
            bf[nt] = *(const bf16x8*)&Bs[cur][(wc + nt * 16 + l15) * BK + l4 * 8];
#pragma unroll
        for (int mt = 0; mt < MT; ++mt)
#pragma unroll
            for (int nt = 0; nt < NT; ++nt)
                acc[mt][nt] = __builtin_amdgcn_mfma_f32_16x16x32_bf16(
                    af[mt], bf[nt], acc[mt][nt], 0, 0, 0);

        asm volatile("s_waitcnt vmcnt(0)" ::: "memory");
        __syncthreads();
    }

#pragma unroll
    for (int mt = 0; mt < MT; ++mt) {
#pragma unroll
        for (int nt = 0; nt < NT; ++nt) {
#pragma unroll
            for (int i = 0; i < 4; ++i) {
                const int row = bm + wr + mt * 16 + l4 * 4 + i;
                const int col = bn + wc + nt * 16 + l15;
                float v = acc[mt][nt][i] + bias[col];
                if constexpr (EPI == 1 || EPI == 3) v = v / (1.f + __expf(-v));  // silu
                if constexpr (EPI == 2 || EPI == 3) v += resid[(size_t)row * N + col];
                if constexpr (EPI == 0 || EPI == 1)
                    ((ushort*)outp)[(size_t)row * N + col] = f2bf(v);
                else
                    ((float*)outp)[(size_t)row * N + col] = v;
            }
        }
    }
}

// ---------------- causal flash attention (MLA), 16 heads, HD=64 ----------------
// grid (32, 16); block 256 = 4 waves x 16 q-rows. KVBLK=128 (halved iteration
// count vs round-3). K,V from fused kvbuf (stride 2048, V = base+1024).
// LDS swizzles (all bijective XOR within a row):
//   Ks  [128 rows][64 d],  128B rows, byte ^= (row&7)<<4
//   VTs [64 d][128 keys],  256B rows, byte ^= (d&15)<<4
//   Ps  [16 rows][128 keys],256B rows, byte ^= (row&15)<<4
__global__ __launch_bounds__(256) void mla_attn_kernel(
    const ushort* __restrict__ Q, const ushort* __restrict__ Kg,
    const ushort* __restrict__ Vg, ushort* __restrict__ O)
{
    constexpr int QSTR = 1024, KSTR = 2048;
    __shared__ alignas(16) ushort Ks[128 * 64];
    __shared__ alignas(16) ushort VTs[64 * 128];
    __shared__ alignas(16) ushort Ps[4][16 * 128];
    const int qb = (int)gridDim.x - 1 - (int)blockIdx.x;   // heavy blocks first
    const int h = blockIdx.y;
    const int tid = threadIdx.x, lane = tid & 63, wave = tid >> 6;
    const int l15 = lane & 15, l4 = lane >> 4;
    const int qrow0 = qb * 64 + wave * 16;

    auto swzK = [&](int row, int colbyte) -> ushort* {
        return (ushort*)((char*)Ks + row * 128 + (colbyte ^ ((row & 7) << 4)));
    };
    auto swzVT = [&](int d, int colbyte) -> ushort* {
        return (ushort*)((char*)VTs + d * 256 + (colbyte ^ ((d & 15) << 4)));
    };
    auto swzP = [&](int row, int colbyte) -> ushort* {
        return (ushort*)((char*)&Ps[wave][0] + row * 256 + (colbyte ^ ((row & 15) << 4)));
    };

    bf16x8 qf[2];
#pragma unroll
    for (int ks = 0; ks < 2; ++ks)
        qf[ks] = *(const bf16x8*)&Q[(size_t)(qrow0 + l15) * QSTR + h * THD + ks * 32 + l4 * 8];

    f32x4 oacc[4] = {};
    float m_run[4], l_run[4];
#pragma unroll
    for (int i = 0; i < 4; ++i) { m_run[i] = -1e30f; l_run[i] = 0.f; }

    // staging: 256 threads x 16B cover 32 rows x 64 cols per round; 4 rounds = 128 rows
    const int sr = tid >> 3, sc = (tid & 7) * 8;
    const ushort* kbase = Kg + (size_t)sr * KSTR + h * THD + sc;
    const ushort* vbase = Vg + (size_t)sr * KSTR + h * THD + sc;

    const int nkt = (qb >> 1) + 1;   // number of 128-key tiles
    uint4 kr[4], vr[4];
#pragma unroll
    for (int r = 0; r < 4; ++r) {
        kr[r] = *(const uint4*)(kbase + (size_t)(r * 32) * KSTR);
        vr[r] = *(const uint4*)(vbase + (size_t)(r * 32) * KSTR);
    }

    for (int kt = 0; kt < nkt; ++kt) {
        __syncthreads();   // all waves done reading Ks/VTs of previous tile
#pragma unroll
        for (int r = 0; r < 4; ++r)
            *(uint4*)swzK(sr + 32 * r, sc * 2) = kr[r];
#pragma unroll
        for (int r = 0; r < 4; ++r) {
            const ushort* p = (const ushort*)&vr[r];
#pragma unroll
            for (int j = 0; j < 8; ++j)
                *swzVT(sc + j, (sr + 32 * r) * 2) = p[j];
        }
        __syncthreads();
        if (kt + 1 < nkt) {
            const size_t off = (size_t)(kt + 1) * 128 * KSTR;
#pragma unroll
            for (int r = 0; r < 4; ++r) {
                kr[r] = *(const uint4*)(kbase + off + (size_t)(r * 32) * KSTR);
                vr[r] = *(const uint4*)(vbase + off + (size_t)(r * 32) * KSTR);
            }
        }

        // ---- scores: s[nt] = Q @ K^T  (16 q-rows x 128 keys) ----
        f32x4 s[8] = {};
        __builtin_amdgcn_s_setprio(1);
#pragma unroll
        for (int ks = 0; ks < 2; ++ks) {
#pragma unroll
            for (int nt = 0; nt < 8; ++nt) {
                const bf16x8 kf = *(const bf16x8*)swzK(nt * 16 + l15, ks * 64 + l4 * 16);
                s[nt] = __builtin_amdgcn_mfma_f32_16x16x32_bf16(qf[ks], kf, s[nt], 0, 0, 0);
            }
        }
        __builtin_amdgcn_s_setprio(0);

        const int kb = kt * 128;
        const bool diag = (kt == nkt - 1);
#pragma unroll
        for (int i = 0; i < 4; ++i) {
            const int qrow = qrow0 + l4 * 4 + i;
            float mx = m_run[i];
#pragma unroll
            for (int nt = 0; nt < 8; ++nt) {
                float v = s[nt][i] * 0.125f;
                if (diag && (kb + nt * 16 + l15 > qrow)) v = -1e30f;
                s[nt][i] = v;
                mx = fmaxf(mx, v);
            }
#pragma unroll
            for (int d = 1; d < 16; d <<= 1) mx = fmaxf(mx, __shfl_xor(mx, d));
            const float alpha = __expf(m_run[i] - mx);
            l_run[i] *= alpha;
#pragma unroll
            for (int nt = 0; nt < 4; ++nt) oacc[nt][i] *= alpha;
            float ps = 0.f;
#pragma unroll
            for (int nt = 0; nt < 8; ++nt) {
                const float p = __expf(s[nt][i] - mx);
                s[nt][i] = p;
                ps += p;
            }
#pragma unroll
            for (int d = 1; d < 16; d <<= 1) ps += __shfl_xor(ps, d);
            l_run[i] += ps;
            m_run[i] = mx;
#pragma unroll
            for (int nt = 0; nt < 8; ++nt)
                *swzP(l4 * 4 + i, (nt * 16 + l15) * 2) = f2bf(s[nt][i]);
        }

        // ---- PV: oacc += P @ V  (Ps per-wave, no cross-wave barrier) ----
        __builtin_amdgcn_s_setprio(1);
#pragma unroll
        for (int ks = 0; ks < 4; ++ks) {
            const bf16x8 pf = *(const bf16x8*)swzP(l15, ks * 64 + l4 * 16);
#pragma unroll
            for (int dt = 0; dt < 4; ++dt) {
                const bf16x8 vf = *(const bf16x8*)swzVT(dt * 16 + l15, ks * 64 + l4 * 16);
                oacc[dt] = __builtin_amdgcn_mfma_f32_16x16x32_bf16(pf, vf, oacc[dt], 0, 0, 0);
            }
        }
        __builtin_amdgcn_s_setprio(0);
    }

#pragma unroll
    for (int dt = 0; dt < 4; ++dt)
#pragma unroll
        for (int i = 0; i < 4; ++i) {
            const int qrow = qrow0 + l4 * 4 + i;
            const float v = oacc[dt][i] / l_run[i];
            O[(size_t)qrow * QSTR + h * THD + dt * 16 + l15] = f2bf(v);
        }
}

// ---------------- launch ----------------
extern "C" void kernel_launch(void* const* d_in, const int* in_sizes, int n_in,
                              void* d_out, int out_size, void* d_ws, size_t ws_size,
                              hipStream_t stream)
{
    const float* x     = (const float*)d_in[0];
    const float* g1    = (const float*)d_in[1];
    const float* Wq    = (const float*)d_in[2];
    const float* bq    = (const float*)d_in[3];
    const float* Wdown = (const float*)d_in[4];
    const float* bdown = (const float*)d_in[5];
    const float* Wk    = (const float*)d_in[6];
    const float* bk    = (const float*)d_in[7];
    const float* Wv    = (const float*)d_in[8];
    const float* bv    = (const float*)d_in[9];
    const float* Wo    = (const float*)d_in[10];
    const float* bo    = (const float*)d_in[11];
    const float* g2    = (const float*)d_in[12];
    const float* W1    = (const float*)d_in[13];
    const float* b1    = (const float*)d_in[14];
    const float* W2    = (const float*)d_in[15];
    const float* b2    = (const float*)d_in[16];
    float* out = (float*)d_out;

    char* ws = (char*)d_ws;
    size_t off = 0;
    auto alloc = [&](size_t bytes) {
        void* p = ws + off;
        off += (bytes + 255) & ~(size_t)255;
        return p;
    };
    ushort* WqT    = (ushort*)alloc((size_t)TH * TD * 2);
    ushort* WdownT = (ushort*)alloc((size_t)TL * TD * 2);
    ushort* WkvT   = (ushort*)alloc((size_t)2 * TH * TL * 2);  // [2048][256]
    ushort* WoT    = (ushort*)alloc((size_t)TD * TH * 2);
    ushort* W1T    = (ushort*)alloc((size_t)TDF * TD * 2);
    ushort* W2T    = (ushort*)alloc((size_t)TD * TDF * 2);
    float*  bkv    = (float*)alloc((size_t)2 * TH * 4);
    ushort* hbuf   = (ushort*)alloc((size_t)TS * TD * 2);
    ushort* cbuf   = (ushort*)alloc((size_t)TS * TL * 2);
    ushort* qbuf   = (ushort*)alloc((size_t)TS * TH * 2);
    ushort* kvbuf  = (ushort*)alloc((size_t)TS * 2 * TH * 2);  // [S][2048]
    ushort* obuf   = (ushort*)alloc((size_t)TS * TH * 2);
    float*  strm   = (float*)alloc((size_t)TS * TD * 4);
    ushort* h2buf  = (ushort*)alloc((size_t)TS * TD * 2);
    ushort* ffn1   = (ushort*)alloc((size_t)TS * TDF * 2);

    const dim3 tb(32, 8);
    transpose_to_bf16<<<dim3(TD / 32, TH / 32), tb, 0, stream>>>(Wq, WqT, TD, TH);
    transpose_to_bf16<<<dim3(TD / 32, TL / 32), tb, 0, stream>>>(Wdown, WdownT, TD, TL);
    transpose_to_bf16<<<dim3(TL / 32, TH / 32), tb, 0, stream>>>(Wk, WkvT, TL, TH);
    transpose_to_bf16<<<dim3(TL / 32, TH / 32), tb, 0, stream>>>(Wv, WkvT + (size_t)TH * TL, TL, TH);
    transpose_to_bf16<<<dim3(TH / 32, TD / 32), tb, 0, stream>>>(Wo, WoT, TH, TD);
    transpose_to_bf16<<<dim3(TD / 32, TDF / 32), tb, 0, stream>>>(W1, W1T, TD, TDF);
    transpose_to_bf16<<<dim3(TDF / 32, TD / 32), tb, 0, stream>>>(W2, W2T, TDF, TD);
    concat_bias_kernel<<<(2 * TH) / 256, 256, 0, stream>>>(bk, bv, bkv, TH);

    rmsnorm_kernel<<<TS, 256, 0, stream>>>(x, g1, hbuf, TD);

    gemm_bf16_kernel<0, 64, 64><<<dim3(TH / 64, TS / 64), 256, 0, stream>>>(
        hbuf, WqT, bq, nullptr, qbuf, TS, TH, TD);
    gemm_bf16_kernel<0, 64, 64><<<dim3(TL / 64, TS / 64), 256, 0, stream>>>(
        hbuf, WdownT, bdown, nullptr, cbuf, TS, TL, TD);
    gemm_bf16_kernel<0, 64, 64><<<dim3(2 * TH / 64, TS / 64), 256, 0, stream>>>(
        cbuf, WkvT, bkv, nullptr, kvbuf, TS, 2 * TH, TL);

    mla_attn_kernel<<<dim3(TS / 64, TNH), 256, 0, stream>>>(
        qbuf, kvbuf, kvbuf + TH, obuf);

    gemm_bf16_kernel<2, 64, 64><<<dim3(TD / 64, TS / 64), 256, 0, stream>>>(
        obuf, WoT, bo, x, strm, TS, TD, TH);

    rmsnorm_kernel<<<TS, 256, 0, stream>>>(strm, g2, h2buf, TD);

    gemm_bf16_kernel<1, 128, 128><<<dim3(TDF / 128, TS / 128), 256, 0, stream>>>(
        h2buf, W1T, b1, nullptr, ffn1, TS, TDF, TD);
    gemm_bf16_kernel<3, 64, 64><<<dim3(TD / 64, TS / 64), 256, 0, stream>>>(
        ffn1, W2T, b2, strm, out, TS, TD, TDF);
}

// Round 7
// 244.809 us; speedup vs baseline: 1.1986x; 1.0911x over previous
//
#include <hip/hip_runtime.h>

// ---------------- types ----------------
typedef __bf16 bf16x8 __attribute__((ext_vector_type(8)));
typedef float  f32x4  __attribute__((ext_vector_type(4)));

static __device__ __forceinline__ ushort f2bf(float f) {
    union { float f; unsigned u; } a; a.f = f;
    unsigned r = a.u + 0x7FFFu + ((a.u >> 16) & 1u);   // RNE
    return (ushort)(r >> 16);
}

// ---------------- constants ----------------
#define TS  2048   // S
#define TD  1024   // D
#define TL  256    // L
#define TH  1024   // H
#define TNH 16
#define THD 64
#define TDF 4096   // 4*D

#define GLD_LDS(gp, lp) \
    __builtin_amdgcn_global_load_lds( \
        (const __attribute__((address_space(1))) unsigned int*)(gp), \
        (__attribute__((address_space(3))) unsigned int*)(lp), 16, 0, 0)

#define WAITV(N) asm volatile("s_waitcnt vmcnt(" #N ")" ::: "memory")

// ---------------- weight transpose + f32->bf16 ----------------
__global__ __launch_bounds__(256) void transpose_to_bf16(
    const float* __restrict__ in, ushort* __restrict__ out, int K, int N)
{
    __shared__ float tile[32][33];
    const int k0 = blockIdx.x * 32, n0 = blockIdx.y * 32;
    const int tx = threadIdx.x, ty = threadIdx.y;   // block (32,8)
#pragma unroll
    for (int i = ty; i < 32; i += 8)
        tile[i][tx] = in[(size_t)(k0 + i) * N + n0 + tx];
    __syncthreads();
#pragma unroll
    for (int i = ty; i < 32; i += 8)
        out[(size_t)(n0 + i) * K + k0 + tx] = f2bf(tile[tx][i]);
}

// ---------------- small: concat two bias vectors ----------------
__global__ __launch_bounds__(256) void concat_bias_kernel(
    const float* __restrict__ a, const float* __restrict__ b,
    float* __restrict__ o, int n)
{
    const int i = blockIdx.x * 256 + threadIdx.x;
    o[i] = (i < n) ? a[i] : b[i - n];
}

// ---------------- RMSNorm: f32 in -> bf16 out ----------------
__global__ __launch_bounds__(256) void rmsnorm_kernel(
    const float* __restrict__ x, const float* __restrict__ g,
    ushort* __restrict__ out, int D)
{
    const int row = blockIdx.x;
    const int tid = threadIdx.x;
    const float4 v = ((const float4*)(x + (size_t)row * D))[tid];
    float ss = v.x * v.x + v.y * v.y + v.z * v.z + v.w * v.w;
#pragma unroll
    for (int off = 32; off > 0; off >>= 1) ss += __shfl_down(ss, off);
    __shared__ float sums[4];
    if ((tid & 63) == 0) sums[tid >> 6] = ss;
    __syncthreads();
    const float tot = sums[0] + sums[1] + sums[2] + sums[3];
    const float scale = rsqrtf(tot / (float)D + 1e-6f);
    const float4 gv = ((const float4*)g)[tid];
    ushort4 o;
    o.x = f2bf(v.x * scale * gv.x);
    o.y = f2bf(v.y * scale * gv.y);
    o.z = f2bf(v.z * scale * gv.z);
    o.w = f2bf(v.w * scale * gv.w);
    *(ushort4*)(out + (size_t)row * D + tid * 4) = o;
}

// ---------------- bf16 GEMM: C = A @ BT^T + bias, epilogue -------------------
// 3-deep ring-buffered LDS with COUNTED vmcnt (T4: never drain to 0 in loop).
// Correctness proven in round-5 run; now paired with the proven tile sizes.
// EPI: 0=bf16; 1=silu->bf16; 2=+resid->f32; 3=silu+resid->f32
template <int EPI, int BM, int BN>
__global__ __launch_bounds__(256) void gemm_bf16_kernel(
    const ushort* __restrict__ A, const ushort* __restrict__ BT,
    const float* __restrict__ bias, const float* __restrict__ resid,
    void* __restrict__ outp, int M, int N, int K)
{
    constexpr int BK = 32;
    constexpr int WM = BM / 2, WN = BN / 2;
    constexpr int MT = WM / 16, NT = WN / 16;
    constexpr int NLA = BM / 64, NLB = BN / 64;
    constexpr int LPS = NLA + NLB;                // loads per stage (per wave)
    __shared__ alignas(16) ushort As[3][BM * BK];
    __shared__ alignas(16) ushort Bs[3][BN * BK];
    const int bm = blockIdx.y * BM, bn = blockIdx.x * BN;
    const int tid = threadIdx.x;
    const int lane = tid & 63, wave = tid >> 6;
    const int wr = (wave >> 1) * WM, wc = (wave & 1) * WN;
    const int l15 = lane & 15, l4 = lane >> 4;

    f32x4 acc[MT][NT] = {};

    const int grow = wave * 16 + (lane >> 2);
    const int gcol = (lane & 3) * 8;
    const ushort* Ag = A + (size_t)(bm + grow) * K + gcol;
    const ushort* Bg = BT + (size_t)(bn + grow) * K + gcol;

    auto stage = [&](int buf, int k0) {
#pragma unroll
        for (int i = 0; i < NLA; ++i)
            GLD_LDS(Ag + (size_t)(i * 64) * K + k0, &As[buf][(i * 64 + wave * 16) * BK]);
#pragma unroll
        for (int i = 0; i < NLB; ++i)
            GLD_LDS(Bg + (size_t)(i * 64) * K + k0, &Bs[buf][(i * 64 + wave * 16) * BK]);
    };

    const int nsteps = K / BK;
    stage(0, 0);
    stage(1, BK);

    for (int t = 0; t < nsteps; ++t) {
        const int cur = t % 3;
        if (t + 1 < nsteps) {
            if constexpr (LPS == 2)      WAITV(2);
            else if constexpr (LPS == 3) WAITV(3);
            else                         WAITV(4);
        } else {
            WAITV(0);
        }
        __builtin_amdgcn_s_barrier();
        asm volatile("" ::: "memory");   // keep LDS reads below the barrier
        if (t + 2 < nsteps) stage((t + 2) % 3, (t + 2) * BK);

        bf16x8 af[MT], bf[NT];
#pragma unroll
        for (int mt = 0; mt < MT; ++mt)
            af[mt] = *(const bf16x8*)&As[cur][(wr + mt * 16 + l15) * BK + l4 * 8];
#pragma unroll
        for (int nt = 0; nt < NT; ++nt)
            bf[nt] = *(const bf16x8*)&Bs[cur][(wc + nt * 16 + l15) * BK + l4 * 8];
#pragma unroll
        for (int mt = 0; mt < MT; ++mt)
#pragma unroll
            for (int nt = 0; nt < NT; ++nt)
                acc[mt][nt] = __builtin_amdgcn_mfma_f32_16x16x32_bf16(
                    af[mt], bf[nt], acc[mt][nt], 0, 0, 0);
    }

#pragma unroll
    for (int mt = 0; mt < MT; ++mt) {
#pragma unroll
        for (int nt = 0; nt < NT; ++nt) {
#pragma unroll
            for (int i = 0; i < 4; ++i) {
                const int row = bm + wr + mt * 16 + l4 * 4 + i;
                const int col = bn + wc + nt * 16 + l15;
                float v = acc[mt][nt][i] + bias[col];
                if constexpr (EPI == 1 || EPI == 3) v = v / (1.f + __expf(-v));  // silu
                if constexpr (EPI == 2 || EPI == 3) v += resid[(size_t)row * N + col];
                if constexpr (EPI == 0 || EPI == 1)
                    ((ushort*)outp)[(size_t)row * N + col] = f2bf(v);
                else
                    ((float*)outp)[(size_t)row * N + col] = v;
            }
        }
    }
}

// ---------------- causal flash attention (MLA), 16 heads, HD=64 ----------------
// Round-3 proven structure (KVBLK=64, 4 waves, 24KB LDS) + SWAPPED QK^T:
// s = mfma(K, Q) puts score[key][q] with q = lane&15 -> each lane owns one
// q-row's 16 scores in-register. Softmax row-reduce = in-lane + 2 shfl_xor
// (^16, ^32) instead of 4 rows x 8 shfl. m/l are per-lane scalars.
// P stored to LDS as [q][key] via packed ushort4; PV identical to round 3.
__global__ __launch_bounds__(256) void mla_attn_kernel(
    const ushort* __restrict__ Q, const ushort* __restrict__ Kg,
    const ushort* __restrict__ Vg, ushort* __restrict__ O)
{
    constexpr int QSTR = 1024, KSTR = 2048;
    __shared__ alignas(16) ushort Ks[64 * 64];    // [key][d], lo-swz
    __shared__ alignas(16) ushort VTs[64 * 64];   // [d][key], hi-swz
    __shared__ alignas(16) ushort Ps[4][16 * 64]; // per-wave [q][key], lo-swz
    const int qb = (int)gridDim.x - 1 - (int)blockIdx.x;   // heavy blocks first
    const int h = blockIdx.y;
    const int tid = threadIdx.x, lane = tid & 63, wave = tid >> 6;
    const int l15 = lane & 15, l4 = lane >> 4;
    const int qrow0 = qb * 64 + wave * 16;
    const int myq = qrow0 + l15;   // q-row this lane's softmax state tracks

    auto swzK = [&](int row, int colbyte) -> ushort* {
        return (ushort*)((char*)Ks + row * 128 + (colbyte ^ ((row & 7) << 4)));
    };
    auto swzVT = [&](int d, int colbyte) -> ushort* {
        return (ushort*)((char*)VTs + d * 128 + (colbyte ^ (((d >> 3) & 7) << 4)));
    };
    auto swzP = [&](int row, int colbyte) -> ushort* {
        return (ushort*)((char*)&Ps[wave][0] + row * 128 + (colbyte ^ ((row & 7) << 4)));
    };

    bf16x8 qf[2];
#pragma unroll
    for (int ks = 0; ks < 2; ++ks)
        qf[ks] = *(const bf16x8*)&Q[(size_t)(qrow0 + l15) * QSTR + h * THD + ks * 32 + l4 * 8];

    f32x4 oacc[4] = {};
    float m_run = -1e30f, l_run = 0.f;

    const int sr = tid >> 3, sc = (tid & 7) * 8;  // staging (32 rows x 64 cols)
    const ushort* kbase = Kg + (size_t)sr * KSTR + h * THD + sc;
    const ushort* vbase = Vg + (size_t)sr * KSTR + h * THD + sc;

    uint4 kr0, kr1, vr0, vr1;
    kr0 = *(const uint4*)kbase;
    kr1 = *(const uint4*)(kbase + (size_t)32 * KSTR);
    vr0 = *(const uint4*)vbase;
    vr1 = *(const uint4*)(vbase + (size_t)32 * KSTR);

    for (int kt = 0; kt <= qb; ++kt) {
        __syncthreads();   // all waves done reading Ks/VTs of previous tile
        *(uint4*)swzK(sr, sc * 2) = kr0;
        *(uint4*)swzK(sr + 32, sc * 2) = kr1;
        {
            const ushort* p0 = (const ushort*)&vr0;
            const ushort* p1 = (const ushort*)&vr1;
#pragma unroll
            for (int j = 0; j < 8; ++j) {
                *swzVT(sc + j, sr * 2) = p0[j];
                *swzVT(sc + j, (sr + 32) * 2) = p1[j];
            }
        }
        __syncthreads();
        if (kt < qb) {   // prefetch next tile (latency hides under compute)
            const size_t off = (size_t)(kt + 1) * 64 * KSTR;
            kr0 = *(const uint4*)(kbase + off);
            kr1 = *(const uint4*)(kbase + off + (size_t)32 * KSTR);
            vr0 = *(const uint4*)(vbase + off);
            vr1 = *(const uint4*)(vbase + off + (size_t)32 * KSTR);
        }

        // ---- scores SWAPPED: s[nt] = K @ Q^T -> s[nt][i] = score[key][q=l15]
        //      key = kt*64 + nt*16 + l4*4 + i
        f32x4 s[4] = {};
        __builtin_amdgcn_s_setprio(1);
#pragma unroll
        for (int ks = 0; ks < 2; ++ks) {
#pragma unroll
            for (int nt = 0; nt < 4; ++nt) {
                const bf16x8 kf = *(const bf16x8*)swzK(nt * 16 + l15, ks * 64 + l4 * 16);
                s[nt] = __builtin_amdgcn_mfma_f32_16x16x32_bf16(kf, qf[ks], s[nt], 0, 0, 0);
            }
        }
        __builtin_amdgcn_s_setprio(0);

        const int kb = kt * 64;
        const bool diag = (kt == qb);

        // ---- per-lane softmax for q = myq over this tile's 16 in-lane keys
        float mx = m_run;
#pragma unroll
        for (int nt = 0; nt < 4; ++nt)
#pragma unroll
            for (int i = 0; i < 4; ++i) {
                float v = s[nt][i] * 0.125f;
                if (diag && (kb + nt * 16 + l4 * 4 + i > myq)) v = -1e30f;
                s[nt][i] = v;
                mx = fmaxf(mx, v);
            }
        mx = fmaxf(mx, __shfl_xor(mx, 16));
        mx = fmaxf(mx, __shfl_xor(mx, 32));
        const float alpha = __expf(m_run - mx);
        m_run = mx;
        float ps = 0.f;
#pragma unroll
        for (int nt = 0; nt < 4; ++nt)
#pragma unroll
            for (int i = 0; i < 4; ++i) {
                const float p = __expf(s[nt][i] - mx);
                s[nt][i] = p;
                ps += p;
            }
        ps += __shfl_xor(ps, 16);
        ps += __shfl_xor(ps, 32);
        l_run = l_run * alpha + ps;

        // ---- rescale oacc: row r = l4*4+i needs alpha of lane l15==r (same l4 grp)
        float al[4];
#pragma unroll
        for (int i = 0; i < 4; ++i)
            al[i] = __shfl(alpha, (lane & 48) | (l4 * 4 + i));
#pragma unroll
        for (int dt = 0; dt < 4; ++dt)
#pragma unroll
            for (int i = 0; i < 4; ++i) oacc[dt][i] *= al[i];

        // ---- P -> LDS [q=l15][key], packed 4 keys per store
#pragma unroll
        for (int nt = 0; nt < 4; ++nt) {
            ushort4 pk;
            pk.x = f2bf(s[nt][0]); pk.y = f2bf(s[nt][1]);
            pk.z = f2bf(s[nt][2]); pk.w = f2bf(s[nt][3]);
            *(ushort4*)swzP(l15, nt * 32 + l4 * 8) = pk;
        }

        // ---- PV: oacc += P @ V  (Ps per-wave, no cross-wave barrier) ----
        __builtin_amdgcn_s_setprio(1);
#pragma unroll
        for (int ks = 0; ks < 2; ++ks) {
            const bf16x8 pf = *(const bf16x8*)swzP(l15, ks * 64 + l4 * 16);
#pragma unroll
            for (int dt = 0; dt < 4; ++dt) {
                const bf16x8 vf = *(const bf16x8*)swzVT(dt * 16 + l15, ks * 64 + l4 * 16);
                oacc[dt] = __builtin_amdgcn_mfma_f32_16x16x32_bf16(pf, vf, oacc[dt], 0, 0, 0);
            }
        }
        __builtin_amdgcn_s_setprio(0);
    }

    // ---- epilogue: divide by l (broadcast per-row like alpha) ----
    const float inv = 1.f / l_run;
    float iv[4];
#pragma unroll
    for (int i = 0; i < 4; ++i)
        iv[i] = __shfl(inv, (lane & 48) | (l4 * 4 + i));
#pragma unroll
    for (int dt = 0; dt < 4; ++dt)
#pragma unroll
        for (int i = 0; i < 4; ++i) {
            const int qrow = qrow0 + l4 * 4 + i;
            O[(size_t)qrow * QSTR + h * THD + dt * 16 + l15] = f2bf(oacc[dt][i] * iv[i]);
        }
}

// ---------------- launch ----------------
extern "C" void kernel_launch(void* const* d_in, const int* in_sizes, int n_in,
                              void* d_out, int out_size, void* d_ws, size_t ws_size,
                              hipStream_t stream)
{
    const float* x     = (const float*)d_in[0];
    const float* g1    = (const float*)d_in[1];
    const float* Wq    = (const float*)d_in[2];
    const float* bq    = (const float*)d_in[3];
    const float* Wdown = (const float*)d_in[4];
    const float* bdown = (const float*)d_in[5];
    const float* Wk    = (const float*)d_in[6];
    const float* bk    = (const float*)d_in[7];
    const float* Wv    = (const float*)d_in[8];
    const float* bv    = (const float*)d_in[9];
    const float* Wo    = (const float*)d_in[10];
    const float* bo    = (const float*)d_in[11];
    const float* g2    = (const float*)d_in[12];
    const float* W1    = (const float*)d_in[13];
    const float* b1    = (const float*)d_in[14];
    const float* W2    = (const float*)d_in[15];
    const float* b2    = (const float*)d_in[16];
    float* out = (float*)d_out;

    char* ws = (char*)d_ws;
    size_t off = 0;
    auto alloc = [&](size_t bytes) {
        void* p = ws + off;
        off += (bytes + 255) & ~(size_t)255;
        return p;
    };
    ushort* WqT    = (ushort*)alloc((size_t)TH * TD * 2);
    ushort* WdownT = (ushort*)alloc((size_t)TL * TD * 2);
    ushort* WkvT   = (ushort*)alloc((size_t)2 * TH * TL * 2);  // [2048][256]
    ushort* WoT    = (ushort*)alloc((size_t)TD * TH * 2);
    ushort* W1T    = (ushort*)alloc((size_t)TDF * TD * 2);
    ushort* W2T    = (ushort*)alloc((size_t)TD * TDF * 2);
    float*  bkv    = (float*)alloc((size_t)2 * TH * 4);
    ushort* hbuf   = (ushort*)alloc((size_t)TS * TD * 2);
    ushort* cbuf   = (ushort*)alloc((size_t)TS * TL * 2);
    ushort* qbuf   = (ushort*)alloc((size_t)TS * TH * 2);
    ushort* kvbuf  = (ushort*)alloc((size_t)TS * 2 * TH * 2);  // [S][2048]
    ushort* obuf   = (ushort*)alloc((size_t)TS * TH * 2);
    float*  strm   = (float*)alloc((size_t)TS * TD * 4);
    ushort* h2buf  = (ushort*)alloc((size_t)TS * TD * 2);
    ushort* ffn1   = (ushort*)alloc((size_t)TS * TDF * 2);

    const dim3 tb(32, 8);
    transpose_to_bf16<<<dim3(TD / 32, TH / 32), tb, 0, stream>>>(Wq, WqT, TD, TH);
    transpose_to_bf16<<<dim3(TD / 32, TL / 32), tb, 0, stream>>>(Wdown, WdownT, TD, TL);
    transpose_to_bf16<<<dim3(TL / 32, TH / 32), tb, 0, stream>>>(Wk, WkvT, TL, TH);
    transpose_to_bf16<<<dim3(TL / 32, TH / 32), tb, 0, stream>>>(Wv, WkvT + (size_t)TH * TL, TL, TH);
    transpose_to_bf16<<<dim3(TH / 32, TD / 32), tb, 0, stream>>>(Wo, WoT, TH, TD);
    transpose_to_bf16<<<dim3(TD / 32, TDF / 32), tb, 0, stream>>>(W1, W1T, TD, TDF);
    transpose_to_bf16<<<dim3(TDF / 32, TD / 32), tb, 0, stream>>>(W2, W2T, TDF, TD);
    concat_bias_kernel<<<(2 * TH) / 256, 256, 0, stream>>>(bk, bv, bkv, TH);

    rmsnorm_kernel<<<TS, 256, 0, stream>>>(x, g1, hbuf, TD);

    gemm_bf16_kernel<0, 64, 64><<<dim3(TH / 64, TS / 64), 256, 0, stream>>>(
        hbuf, WqT, bq, nullptr, qbuf, TS, TH, TD);
    gemm_bf16_kernel<0, 64, 64><<<dim3(TL / 64, TS / 64), 256, 0, stream>>>(
        hbuf, WdownT, bdown, nullptr, cbuf, TS, TL, TD);
    gemm_bf16_kernel<0, 64, 64><<<dim3(2 * TH / 64, TS / 64), 256, 0, stream>>>(
        cbuf, WkvT, bkv, nullptr, kvbuf, TS, 2 * TH, TL);

    mla_attn_kernel<<<dim3(TS / 64, TNH), 256, 0, stream>>>(
        qbuf, kvbuf, kvbuf + TH, obuf);

    gemm_bf16_kernel<2, 64, 64><<<dim3(TD / 64, TS / 64), 256, 0, stream>>>(
        obuf, WoT, bo, x, strm, TS, TD, TH);

    rmsnorm_kernel<<<TS, 256, 0, stream>>>(strm, g2, h2buf, TD);

    gemm_bf16_kernel<1, 128, 128><<<dim3(TDF / 128, TS / 128), 256, 0, stream>>>(
        h2buf, W1T, b1, nullptr, ffn1, TS, TDF, TD);
    gemm_bf16_kernel<3, 64, 64><<<dim3(TD / 64, TS / 64), 256, 0, stream>>>(
        ffn1, W2T, b2, strm, out, TS, TD, TDF);
}

// Round 8
// 232.204 us; speedup vs baseline: 1.2636x; 1.0543x over previous
//
#include <hip/hip_runtime.h>

// ---------------- types ----------------
typedef __bf16 bf16x8 __attribute__((ext_vector_type(8)));
typedef float  f32x4  __attribute__((ext_vector_type(4)));

static __device__ __forceinline__ ushort f2bf(float f) {
    union { float f; unsigned u; } a; a.f = f;
    unsigned r = a.u + 0x7FFFu + ((a.u >> 16) & 1u);   // RNE
    return (ushort)(r >> 16);
}

// ---------------- constants ----------------
#define TS  2048   // S
#define TD  1024   // D
#define TL  256    // L
#define TH  1024   // H
#define TNH 16
#define THD 64
#define TDF 4096   // 4*D

#define GLD_LDS(gp, lp) \
    __builtin_amdgcn_global_load_lds( \
        (const __attribute__((address_space(1))) unsigned int*)(gp), \
        (__attribute__((address_space(3))) unsigned int*)(lp), 16, 0, 0)

// ---------------- weight transpose + f32->bf16 ----------------
__global__ __launch_bounds__(256) void transpose_to_bf16(
    const float* __restrict__ in, ushort* __restrict__ out, int K, int N)
{
    __shared__ float tile[32][33];
    const int k0 = blockIdx.x * 32, n0 = blockIdx.y * 32;
    const int tx = threadIdx.x, ty = threadIdx.y;   // block (32,8)
#pragma unroll
    for (int i = ty; i < 32; i += 8)
        tile[i][tx] = in[(size_t)(k0 + i) * N + n0 + tx];
    __syncthreads();
#pragma unroll
    for (int i = ty; i < 32; i += 8)
        out[(size_t)(n0 + i) * K + k0 + tx] = f2bf(tile[tx][i]);
}

// ---------------- small: concat two bias vectors ----------------
__global__ __launch_bounds__(256) void concat_bias_kernel(
    const float* __restrict__ a, const float* __restrict__ b,
    float* __restrict__ o, int n)
{
    const int i = blockIdx.x * 256 + threadIdx.x;
    o[i] = (i < n) ? a[i] : b[i - n];
}

// ---------------- RMSNorm: f32 in -> bf16 out ----------------
__global__ __launch_bounds__(256) void rmsnorm_kernel(
    const float* __restrict__ x, const float* __restrict__ g,
    ushort* __restrict__ out, int D)
{
    const int row = blockIdx.x;
    const int tid = threadIdx.x;
    const float4 v = ((const float4*)(x + (size_t)row * D))[tid];
    float ss = v.x * v.x + v.y * v.y + v.z * v.z + v.w * v.w;
#pragma unroll
    for (int off = 32; off > 0; off >>= 1) ss += __shfl_down(ss, off);
    __shared__ float sums[4];
    if ((tid & 63) == 0) sums[tid >> 6] = ss;
    __syncthreads();
    const float tot = sums[0] + sums[1] + sums[2] + sums[3];
    const float scale = rsqrtf(tot / (float)D + 1e-6f);
    const float4 gv = ((const float4*)g)[tid];
    ushort4 o;
    o.x = f2bf(v.x * scale * gv.x);
    o.y = f2bf(v.y * scale * gv.y);
    o.z = f2bf(v.z * scale * gv.z);
    o.w = f2bf(v.w * scale * gv.w);
    *(ushort4*)(out + (size_t)row * D + tid * 4) = o;
}

// ---------------- bf16 GEMM (2-phase, round-6 proven): C = A @ BT^T + bias --
// 2-phase double-buffered LDS, global_load_lds(16B), vmcnt(0)+barrier AFTER
// the MFMA block (loads complete under compute). Ring-3 counted-vmcnt variant
// measured WORSE (round 6 vs 7 A/B: +14us aggregate) -- keep 2-phase.
// EPI: 0=bf16; 1=silu->bf16; 2=+resid->f32; 3=silu+resid->f32
template <int EPI, int BM, int BN>
__global__ __launch_bounds__(256) void gemm_bf16_kernel(
    const ushort* __restrict__ A, const ushort* __restrict__ BT,
    const float* __restrict__ bias, const float* __restrict__ resid,
    void* __restrict__ outp, int M, int N, int K)
{
    constexpr int BK = 32;
    constexpr int WM = BM / 2, WN = BN / 2;
    constexpr int MT = WM / 16, NT = WN / 16;
    constexpr int NLA = BM / 64, NLB = BN / 64;
    __shared__ alignas(16) ushort As[2][BM * BK];
    __shared__ alignas(16) ushort Bs[2][BN * BK];
    const int bm = blockIdx.y * BM, bn = blockIdx.x * BN;
    const int tid = threadIdx.x;
    const int lane = tid & 63, wave = tid >> 6;
    const int wr = (wave >> 1) * WM, wc = (wave & 1) * WN;
    const int l15 = lane & 15, l4 = lane >> 4;

    f32x4 acc[MT][NT] = {};

    const int grow = wave * 16 + (lane >> 2);
    const int gcol = (lane & 3) * 8;
    const ushort* Ag = A + (size_t)(bm + grow) * K + gcol;
    const ushort* Bg = BT + (size_t)(bn + grow) * K + gcol;

    auto stage = [&](int buf, int k0) {
#pragma unroll
        for (int i = 0; i < NLA; ++i)
            GLD_LDS(Ag + (size_t)(i * 64) * K + k0, &As[buf][(i * 64 + wave * 16) * BK]);
#pragma unroll
        for (int i = 0; i < NLB; ++i)
            GLD_LDS(Bg + (size_t)(i * 64) * K + k0, &Bs[buf][(i * 64 + wave * 16) * BK]);
    };

    stage(0, 0);
    asm volatile("s_waitcnt vmcnt(0)" ::: "memory");
    __syncthreads();

    const int nsteps = K / BK;
    for (int t = 0; t < nsteps; ++t) {
        const int cur = t & 1;
        if (t + 1 < nsteps) stage(cur ^ 1, (t + 1) * BK);

        bf16x8 af[MT], bf[NT];
#pragma unroll
        for (int mt = 0; mt < MT; ++mt)
            af[mt] = *(const bf16x8*)&As[cur][(wr + mt * 16 + l15) * BK + l4 * 8];
#pragma unroll
        for (int nt = 0; nt < NT; ++nt)
            bf[nt] = *(const bf16x8*)&Bs[cur][(wc + nt * 16 + l15) * BK + l4 * 8];
#pragma unroll
        for (int mt = 0; mt < MT; ++mt)
#pragma unroll
            for (int nt = 0; nt < NT; ++nt)
                acc[mt][nt] = __builtin_amdgcn_mfma_f32_16x16x32_bf16(
                    af[mt], bf[nt], acc[mt][nt], 0, 0, 0);

        asm volatile("s_waitcnt vmcnt(0)" ::: "memory");
        __syncthreads();
    }

#pragma unroll
    for (int mt = 0; mt < MT; ++mt) {
#pragma unroll
        for (int nt = 0; nt < NT; ++nt) {
#pragma unroll
            for (int i = 0; i < 4; ++i) {
                const int row = bm + wr + mt * 16 + l4 * 4 + i;
                const int col = bn + wc + nt * 16 + l15;
                float v = acc[mt][nt][i] + bias[col];
                if constexpr (EPI == 1 || EPI == 3) v = v / (1.f + __expf(-v));  // silu
                if constexpr (EPI == 2 || EPI == 3) v += resid[(size_t)row * N + col];
                if constexpr (EPI == 0 || EPI == 1)
                    ((ushort*)outp)[(size_t)row * N + col] = f2bf(v);
                else
                    ((float*)outp)[(size_t)row * N + col] = v;
            }
        }
    }
}

// ---------------- causal flash attention (MLA), 16 heads, HD=64 ----------------
// Swapped QK^T (per-lane softmax, round-7 proven) + DOUBLE-BUFFERED K/V LDS:
// ONE barrier per KV tile; staging of tile t+1 overlaps compute of tile t.
// Per iter: sync -> ds_write tile t+1 -> issue global load t+2 -> compute t.
__global__ __launch_bounds__(256) void mla_attn_kernel(
    const ushort* __restrict__ Q, const ushort* __restrict__ Kg,
    const ushort* __restrict__ Vg, ushort* __restrict__ O)
{
    constexpr int QSTR = 1024, KSTR = 2048;
    __shared__ alignas(16) ushort Ks[2][64 * 64];    // [buf][key][d], lo-swz
    __shared__ alignas(16) ushort VTs[2][64 * 64];   // [buf][d][key], hi-swz
    __shared__ alignas(16) ushort Ps[4][16 * 64];    // per-wave [q][key], lo-swz
    const int qb = (int)gridDim.x - 1 - (int)blockIdx.x;   // heavy blocks first
    const int h = blockIdx.y;
    const int tid = threadIdx.x, lane = tid & 63, wave = tid >> 6;
    const int l15 = lane & 15, l4 = lane >> 4;
    const int qrow0 = qb * 64 + wave * 16;
    const int myq = qrow0 + l15;   // q-row this lane's softmax state tracks

    auto swzK = [](ushort* base, int row, int colbyte) -> ushort* {
        return (ushort*)((char*)base + row * 128 + (colbyte ^ ((row & 7) << 4)));
    };
    auto swzVT = [](ushort* base, int d, int colbyte) -> ushort* {
        return (ushort*)((char*)base + d * 128 + (colbyte ^ (((d >> 3) & 7) << 4)));
    };
    auto swzP = [&](int row, int colbyte) -> ushort* {
        return (ushort*)((char*)&Ps[wave][0] + row * 128 + (colbyte ^ ((row & 7) << 4)));
    };

    bf16x8 qf[2];
#pragma unroll
    for (int ks = 0; ks < 2; ++ks)
        qf[ks] = *(const bf16x8*)&Q[(size_t)(qrow0 + l15) * QSTR + h * THD + ks * 32 + l4 * 8];

    f32x4 oacc[4] = {};
    float m_run = -1e30f, l_run = 0.f;

    const int sr = tid >> 3, sc = (tid & 7) * 8;  // staging (32 rows x 64 cols)
    const ushort* kbase = Kg + (size_t)sr * KSTR + h * THD + sc;
    const ushort* vbase = Vg + (size_t)sr * KSTR + h * THD + sc;

    // ---- prologue: stage tile 0 into buf 0; prefetch tile 1 into regs ----
    uint4 kr0, kr1, vr0, vr1;
    kr0 = *(const uint4*)kbase;
    kr1 = *(const uint4*)(kbase + (size_t)32 * KSTR);
    vr0 = *(const uint4*)vbase;
    vr1 = *(const uint4*)(vbase + (size_t)32 * KSTR);
    {
        *(uint4*)swzK(&Ks[0][0], sr, sc * 2) = kr0;
        *(uint4*)swzK(&Ks[0][0], sr + 32, sc * 2) = kr1;
        const ushort* p0 = (const ushort*)&vr0;
        const ushort* p1 = (const ushort*)&vr1;
#pragma unroll
        for (int j = 0; j < 8; ++j) {
            *swzVT(&VTs[0][0], sc + j, sr * 2) = p0[j];
            *swzVT(&VTs[0][0], sc + j, (sr + 32) * 2) = p1[j];
        }
    }
    if (qb >= 1) {
        const size_t off = (size_t)64 * KSTR;
        kr0 = *(const uint4*)(kbase + off);
        kr1 = *(const uint4*)(kbase + off + (size_t)32 * KSTR);
        vr0 = *(const uint4*)(vbase + off);
        vr1 = *(const uint4*)(vbase + off + (size_t)32 * KSTR);
    }

    for (int kt = 0; kt <= qb; ++kt) {
        __syncthreads();   // tile kt staged; readers of buf[(kt+1)&1] done
        if (kt < qb) {
            // ---- stage tile kt+1 into the other buffer (overlaps compute) ----
            ushort* kd = &Ks[(kt + 1) & 1][0];
            ushort* vd = &VTs[(kt + 1) & 1][0];
            *(uint4*)swzK(kd, sr, sc * 2) = kr0;
            *(uint4*)swzK(kd, sr + 32, sc * 2) = kr1;
            const ushort* p0 = (const ushort*)&vr0;
            const ushort* p1 = (const ushort*)&vr1;
#pragma unroll
            for (int j = 0; j < 8; ++j) {
                *swzVT(vd, sc + j, sr * 2) = p0[j];
                *swzVT(vd, sc + j, (sr + 32) * 2) = p1[j];
            }
            if (kt + 1 < qb) {   // prefetch tile kt+2 into regs
                const size_t off = (size_t)(kt + 2) * 64 * KSTR;
                kr0 = *(const uint4*)(kbase + off);
                kr1 = *(const uint4*)(kbase + off + (size_t)32 * KSTR);
                vr0 = *(const uint4*)(vbase + off);
                vr1 = *(const uint4*)(vbase + off + (size_t)32 * KSTR);
            }
        }
        const ushort* kb_lds = &Ks[kt & 1][0];
        const ushort* vb_lds = &VTs[kt & 1][0];

        // ---- scores SWAPPED: s[nt] = K @ Q^T -> s[nt][i] = score[key][q=l15]
        f32x4 s[4] = {};
        __builtin_amdgcn_s_setprio(1);
#pragma unroll
        for (int ks = 0; ks < 2; ++ks) {
#pragma unroll
            for (int nt = 0; nt < 4; ++nt) {
                const bf16x8 kf = *(const bf16x8*)swzK((ushort*)kb_lds, nt * 16 + l15, ks * 64 + l4 * 16);
                s[nt] = __builtin_amdgcn_mfma_f32_16x16x32_bf16(kf, qf[ks], s[nt], 0, 0, 0);
            }
        }
        __builtin_amdgcn_s_setprio(0);

        const int kb = kt * 64;
        const bool diag = (kt == qb);

        // ---- per-lane softmax for q = myq over this tile's 16 in-lane keys
        float mx = m_run;
#pragma unroll
        for (int nt = 0; nt < 4; ++nt)
#pragma unroll
            for (int i = 0; i < 4; ++i) {
                float v = s[nt][i] * 0.125f;
                if (diag && (kb + nt * 16 + l4 * 4 + i > myq)) v = -1e30f;
                s[nt][i] = v;
                mx = fmaxf(mx, v);
            }
        mx = fmaxf(mx, __shfl_xor(mx, 16));
        mx = fmaxf(mx, __shfl_xor(mx, 32));
        const float alpha = __expf(m_run - mx);
        m_run = mx;
        float ps = 0.f;
#pragma unroll
        for (int nt = 0; nt < 4; ++nt)
#pragma unroll
            for (int i = 0; i < 4; ++i) {
                const float p = __expf(s[nt][i] - mx);
                s[nt][i] = p;
                ps += p;
            }
        ps += __shfl_xor(ps, 16);
        ps += __shfl_xor(ps, 32);
        l_run = l_run * alpha + ps;

        // ---- rescale oacc: row r = l4*4+i needs alpha of lane l15==r
        float al[4];
#pragma unroll
        for (int i = 0; i < 4; ++i)
            al[i] = __shfl(alpha, (lane & 48) | (l4 * 4 + i));
#pragma unroll
        for (int dt = 0; dt < 4; ++dt)
#pragma unroll
            for (int i = 0; i < 4; ++i) oacc[dt][i] *= al[i];

        // ---- P -> LDS [q=l15][key], packed 4 keys per store
#pragma unroll
        for (int nt = 0; nt < 4; ++nt) {
            ushort4 pk;
            pk.x = f2bf(s[nt][0]); pk.y = f2bf(s[nt][1]);
            pk.z = f2bf(s[nt][2]); pk.w = f2bf(s[nt][3]);
            *(ushort4*)swzP(l15, nt * 32 + l4 * 8) = pk;
        }

        // ---- PV: oacc += P @ V  (Ps per-wave, no cross-wave barrier) ----
        __builtin_amdgcn_s_setprio(1);
#pragma unroll
        for (int ks = 0; ks < 2; ++ks) {
            const bf16x8 pf = *(const bf16x8*)swzP(l15, ks * 64 + l4 * 16);
#pragma unroll
            for (int dt = 0; dt < 4; ++dt) {
                const bf16x8 vf = *(const bf16x8*)swzVT((ushort*)vb_lds, dt * 16 + l15, ks * 64 + l4 * 16);
                oacc[dt] = __builtin_amdgcn_mfma_f32_16x16x32_bf16(pf, vf, oacc[dt], 0, 0, 0);
            }
        }
        __builtin_amdgcn_s_setprio(0);
    }

    // ---- epilogue: divide by l (broadcast per-row like alpha) ----
    const float inv = 1.f / l_run;
    float iv[4];
#pragma unroll
    for (int i = 0; i < 4; ++i)
        iv[i] = __shfl(inv, (lane & 48) | (l4 * 4 + i));
#pragma unroll
    for (int dt = 0; dt < 4; ++dt)
#pragma unroll
        for (int i = 0; i < 4; ++i) {
            const int qrow = qrow0 + l4 * 4 + i;
            O[(size_t)qrow * QSTR + h * THD + dt * 16 + l15] = f2bf(oacc[dt][i] * iv[i]);
        }
}

// ---------------- launch ----------------
extern "C" void kernel_launch(void* const* d_in, const int* in_sizes, int n_in,
                              void* d_out, int out_size, void* d_ws, size_t ws_size,
                              hipStream_t stream)
{
    const float* x     = (const float*)d_in[0];
    const float* g1    = (const float*)d_in[1];
    const float* Wq    = (const float*)d_in[2];
    const float* bq    = (const float*)d_in[3];
    const float* Wdown = (const float*)d_in[4];
    const float* bdown = (const float*)d_in[5];
    const float* Wk    = (const float*)d_in[6];
    const float* bk    = (const float*)d_in[7];
    const float* Wv    = (const float*)d_in[8];
    const float* bv    = (const float*)d_in[9];
    const float* Wo    = (const float*)d_in[10];
    const float* bo    = (const float*)d_in[11];
    const float* g2    = (const float*)d_in[12];
    const float* W1    = (const float*)d_in[13];
    const float* b1    = (const float*)d_in[14];
    const float* W2    = (const float*)d_in[15];
    const float* b2    = (const float*)d_in[16];
    float* out = (float*)d_out;

    char* ws = (char*)d_ws;
    size_t off = 0;
    auto alloc = [&](size_t bytes) {
        void* p = ws + off;
        off += (bytes + 255) & ~(size_t)255;
        return p;
    };
    ushort* WqT    = (ushort*)alloc((size_t)TH * TD * 2);
    ushort* WdownT = (ushort*)alloc((size_t)TL * TD * 2);
    ushort* WkvT   = (ushort*)alloc((size_t)2 * TH * TL * 2);  // [2048][256]
    ushort* WoT    = (ushort*)alloc((size_t)TD * TH * 2);
    ushort* W1T    = (ushort*)alloc((size_t)TDF * TD * 2);
    ushort* W2T    = (ushort*)alloc((size_t)TD * TDF * 2);
    float*  bkv    = (float*)alloc((size_t)2 * TH * 4);
    ushort* hbuf   = (ushort*)alloc((size_t)TS * TD * 2);
    ushort* cbuf   = (ushort*)alloc((size_t)TS * TL * 2);
    ushort* qbuf   = (ushort*)alloc((size_t)TS * TH * 2);
    ushort* kvbuf  = (ushort*)alloc((size_t)TS * 2 * TH * 2);  // [S][2048]
    ushort* obuf   = (ushort*)alloc((size_t)TS * TH * 2);
    float*  strm   = (float*)alloc((size_t)TS * TD * 4);
    ushort* h2buf  = (ushort*)alloc((size_t)TS * TD * 2);
    ushort* ffn1   = (ushort*)alloc((size_t)TS * TDF * 2);

    const dim3 tb(32, 8);
    transpose_to_bf16<<<dim3(TD / 32, TH / 32), tb, 0, stream>>>(Wq, WqT, TD, TH);
    transpose_to_bf16<<<dim3(TD / 32, TL / 32), tb, 0, stream>>>(Wdown, WdownT, TD, TL);
    transpose_to_bf16<<<dim3(TL / 32, TH / 32), tb, 0, stream>>>(Wk, WkvT, TL, TH);
    transpose_to_bf16<<<dim3(TL / 32, TH / 32), tb, 0, stream>>>(Wv, WkvT + (size_t)TH * TL, TL, TH);
    transpose_to_bf16<<<dim3(TH / 32, TD / 32), tb, 0, stream>>>(Wo, WoT, TH, TD);
    transpose_to_bf16<<<dim3(TD / 32, TDF / 32), tb, 0, stream>>>(W1, W1T, TD, TDF);
    transpose_to_bf16<<<dim3(TDF / 32, TD / 32), tb, 0, stream>>>(W2, W2T, TDF, TD);
    concat_bias_kernel<<<(2 * TH) / 256, 256, 0, stream>>>(bk, bv, bkv, TH);

    rmsnorm_kernel<<<TS, 256, 0, stream>>>(x, g1, hbuf, TD);

    gemm_bf16_kernel<0, 64, 64><<<dim3(TH / 64, TS / 64), 256, 0, stream>>>(
        hbuf, WqT, bq, nullptr, qbuf, TS, TH, TD);
    gemm_bf16_kernel<0, 64, 64><<<dim3(TL / 64, TS / 64), 256, 0, stream>>>(
        hbuf, WdownT, bdown, nullptr, cbuf, TS, TL, TD);
    gemm_bf16_kernel<0, 64, 64><<<dim3(2 * TH / 64, TS / 64), 256, 0, stream>>>(
        cbuf, WkvT, bkv, nullptr, kvbuf, TS, 2 * TH, TL);

    mla_attn_kernel<<<dim3(TS / 64, TNH), 256, 0, stream>>>(
        qbuf, kvbuf, kvbuf + TH, obuf);

    gemm_bf16_kernel<2, 64, 64><<<dim3(TD / 64, TS / 64), 256, 0, stream>>>(
        obuf, WoT, bo, x, strm, TS, TD, TH);

    rmsnorm_kernel<<<TS, 256, 0, stream>>>(strm, g2, h2buf, TD);

    gemm_bf16_kernel<1, 128, 128><<<dim3(TDF / 128, TS / 128), 256, 0, stream>>>(
        h2buf, W1T, b1, nullptr, ffn1, TS, TDF, TD);
    gemm_bf16_kernel<3, 64, 64><<<dim3(TD / 64, TS / 64), 256, 0, stream>>>(
        ffn1, W2T, b2, strm, out, TS, TD, TDF);
}

// Round 9
// 231.511 us; speedup vs baseline: 1.2674x; 1.0030x over previous
//
#include <hip/hip_runtime.h>

// ---------------- types ----------------
typedef __bf16 bf16x8 __attribute__((ext_vector_type(8)));
typedef float  f32x4  __attribute__((ext_vector_type(4)));

static __device__ __forceinline__ ushort f2bf(float f) {
    union { float f; unsigned u; } a; a.f = f;
    unsigned r = a.u + 0x7FFFu + ((a.u >> 16) & 1u);   // RNE
    return (ushort)(r >> 16);
}
static __device__ __forceinline__ ushort f2bf_hw(float f) {
    __bf16 b = (__bf16)f;                               // HW cvt (RNE), pairs -> cvt_pk
    return __builtin_bit_cast(ushort, b);
}

// ---------------- constants ----------------
#define TS  2048   // S
#define TD  1024   // D
#define TL  256    // L
#define TH  1024   // H
#define TNH 16
#define THD 64
#define TDF 4096   // 4*D

#define GLD_LDS(gp, lp) \
    __builtin_amdgcn_global_load_lds( \
        (const __attribute__((address_space(1))) unsigned int*)(gp), \
        (__attribute__((address_space(3))) unsigned int*)(lp), 16, 0, 0)

// ---------------- weight transpose + f32->bf16 ----------------
__global__ __launch_bounds__(256) void transpose_to_bf16(
    const float* __restrict__ in, ushort* __restrict__ out, int K, int N)
{
    __shared__ float tile[32][33];
    const int k0 = blockIdx.x * 32, n0 = blockIdx.y * 32;
    const int tx = threadIdx.x, ty = threadIdx.y;   // block (32,8)
#pragma unroll
    for (int i = ty; i < 32; i += 8)
        tile[i][tx] = in[(size_t)(k0 + i) * N + n0 + tx];
    __syncthreads();
#pragma unroll
    for (int i = ty; i < 32; i += 8)
        out[(size_t)(n0 + i) * K + k0 + tx] = f2bf(tile[tx][i]);
}

// ---------------- small: concat two bias vectors ----------------
__global__ __launch_bounds__(256) void concat_bias_kernel(
    const float* __restrict__ a, const float* __restrict__ b,
    float* __restrict__ o, int n)
{
    const int i = blockIdx.x * 256 + threadIdx.x;
    o[i] = (i < n) ? a[i] : b[i - n];
}

// ---------------- RMSNorm: f32 in -> bf16 out ----------------
__global__ __launch_bounds__(256) void rmsnorm_kernel(
    const float* __restrict__ x, const float* __restrict__ g,
    ushort* __restrict__ out, int D)
{
    const int row = blockIdx.x;
    const int tid = threadIdx.x;
    const float4 v = ((const float4*)(x + (size_t)row * D))[tid];
    float ss = v.x * v.x + v.y * v.y + v.z * v.z + v.w * v.w;
#pragma unroll
    for (int off = 32; off > 0; off >>= 1) ss += __shfl_down(ss, off);
    __shared__ float sums[4];
    if ((tid & 63) == 0) sums[tid >> 6] = ss;
    __syncthreads();
    const float tot = sums[0] + sums[1] + sums[2] + sums[3];
    const float scale = rsqrtf(tot / (float)D + 1e-6f);
    const float4 gv = ((const float4*)g)[tid];
    ushort4 o;
    o.x = f2bf(v.x * scale * gv.x);
    o.y = f2bf(v.y * scale * gv.y);
    o.z = f2bf(v.z * scale * gv.z);
    o.w = f2bf(v.w * scale * gv.w);
    *(ushort4*)(out + (size_t)row * D + tid * 4) = o;
}

// ---------------- bf16 GEMM (2-phase, twice-validated): C = A @ BT^T + bias -
// 2-phase double-buffered LDS, global_load_lds(16B), vmcnt(0)+barrier AFTER
// the MFMA block. EPI: 0=bf16; 1=silu->bf16; 2=+resid->f32; 3=silu+resid->f32
template <int EPI, int BM, int BN>
__global__ __launch_bounds__(256) void gemm_bf16_kernel(
    const ushort* __restrict__ A, const ushort* __restrict__ BT,
    const float* __restrict__ bias, const float* __restrict__ resid,
    void* __restrict__ outp, int M, int N, int K)
{
    constexpr int BK = 32;
    constexpr int WM = BM / 2, WN = BN / 2;
    constexpr int MT = WM / 16, NT = WN / 16;
    constexpr int NLA = BM / 64, NLB = BN / 64;
    __shared__ alignas(16) ushort As[2][BM * BK];
    __shared__ alignas(16) ushort Bs[2][BN * BK];
    const int bm = blockIdx.y * BM, bn = blockIdx.x * BN;
    const int tid = threadIdx.x;
    const int lane = tid & 63, wave = tid >> 6;
    const int wr = (wave >> 1) * WM, wc = (wave & 1) * WN;
    const int l15 = lane & 15, l4 = lane >> 4;

    f32x4 acc[MT][NT] = {};

    const int grow = wave * 16 + (lane >> 2);
    const int gcol = (lane & 3) * 8;
    const ushort* Ag = A + (size_t)(bm + grow) * K + gcol;
    const ushort* Bg = BT + (size_t)(bn + grow) * K + gcol;

    auto stage = [&](int buf, int k0) {
#pragma unroll
        for (int i = 0; i < NLA; ++i)
            GLD_LDS(Ag + (size_t)(i * 64) * K + k0, &As[buf][(i * 64 + wave * 16) * BK]);
#pragma unroll
        for (int i = 0; i < NLB; ++i)
            GLD_LDS(Bg + (size_t)(i * 64) * K + k0, &Bs[buf][(i * 64 + wave * 16) * BK]);
    };

    stage(0, 0);
    asm volatile("s_waitcnt vmcnt(0)" ::: "memory");
    __syncthreads();

    const int nsteps = K / BK;
    for (int t = 0; t < nsteps; ++t) {
        const int cur = t & 1;
        if (t + 1 < nsteps) stage(cur ^ 1, (t + 1) * BK);

        bf16x8 af[MT], bf[NT];
#pragma unroll
        for (int mt = 0; mt < MT; ++mt)
            af[mt] = *(const bf16x8*)&As[cur][(wr + mt * 16 + l15) * BK + l4 * 8];
#pragma unroll
        for (int nt = 0; nt < NT; ++nt)
            bf[nt] = *(const bf16x8*)&Bs[cur][(wc + nt * 16 + l15) * BK + l4 * 8];
#pragma unroll
        for (int mt = 0; mt < MT; ++mt)
#pragma unroll
            for (int nt = 0; nt < NT; ++nt)
                acc[mt][nt] = __builtin_amdgcn_mfma_f32_16x16x32_bf16(
                    af[mt], bf[nt], acc[mt][nt], 0, 0, 0);

        asm volatile("s_waitcnt vmcnt(0)" ::: "memory");
        __syncthreads();
    }

#pragma unroll
    for (int mt = 0; mt < MT; ++mt) {
#pragma unroll
        for (int nt = 0; nt < NT; ++nt) {
#pragma unroll
            for (int i = 0; i < 4; ++i) {
                const int row = bm + wr + mt * 16 + l4 * 4 + i;
                const int col = bn + wc + nt * 16 + l15;
                float v = acc[mt][nt][i] + bias[col];
                if constexpr (EPI == 1 || EPI == 3) v = v / (1.f + __expf(-v));  // silu
                if constexpr (EPI == 2 || EPI == 3) v += resid[(size_t)row * N + col];
                if constexpr (EPI == 0 || EPI == 1)
                    ((ushort*)outp)[(size_t)row * N + col] = f2bf(v);
                else
                    ((float*)outp)[(size_t)row * N + col] = v;
            }
        }
    }
}

// ---------------- causal flash attention (MLA), 16 heads, HD=64 ----------------
// Swapped QK^T (per-lane softmax) + swapped PV (per-lane rescale: oacc holds
// o[d][q=l15], so alpha/1/l are the lane's OWN scalars -- zero broadcasts) +
// diag-mask hoisted to the last tile only + exp2 with folded scale + HW bf16
// converts. Double-buffered K/V LDS, one barrier per tile.
__global__ __launch_bounds__(256) void mla_attn_kernel(
    const ushort* __restrict__ Q, const ushort* __restrict__ Kg,
    const ushort* __restrict__ Vg, ushort* __restrict__ O)
{
    constexpr int QSTR = 1024, KSTR = 2048;
    constexpr float CE = 0.125f * 1.44269504f;   // scale * log2(e)
    __shared__ alignas(16) ushort Ks[2][64 * 64];    // [buf][key][d], lo-swz
    __shared__ alignas(16) ushort VTs[2][64 * 64];   // [buf][d][key], hi-swz
    __shared__ alignas(16) ushort Ps[4][16 * 64];    // per-wave [q][key], lo-swz
    const int qb = (int)gridDim.x - 1 - (int)blockIdx.x;   // heavy blocks first
    const int h = blockIdx.y;
    const int tid = threadIdx.x, lane = tid & 63, wave = tid >> 6;
    const int l15 = lane & 15, l4 = lane >> 4;
    const int qrow0 = qb * 64 + wave * 16;
    const int myq = qrow0 + l15;   // q-row this lane's softmax state tracks

    auto swzK = [](ushort* base, int row, int colbyte) -> ushort* {
        return (ushort*)((char*)base + row * 128 + (colbyte ^ ((row & 7) << 4)));
    };
    auto swzVT = [](ushort* base, int d, int colbyte) -> ushort* {
        return (ushort*)((char*)base + d * 128 + (colbyte ^ (((d >> 3) & 7) << 4)));
    };
    auto swzP = [&](int row, int colbyte) -> ushort* {
        return (ushort*)((char*)&Ps[wave][0] + row * 128 + (colbyte ^ ((row & 7) << 4)));
    };

    bf16x8 qf[2];
#pragma unroll
    for (int ks = 0; ks < 2; ++ks)
        qf[ks] = *(const bf16x8*)&Q[(size_t)(qrow0 + l15) * QSTR + h * THD + ks * 32 + l4 * 8];

    f32x4 oacc[4] = {};          // oacc[dt][i] = o[d = dt*16 + l4*4 + i][q = myq]
    float m_run = -1e30f, l_run = 0.f;   // raw-score domain

    const int sr = tid >> 3, sc = (tid & 7) * 8;  // staging (32 rows x 64 cols)
    const ushort* kbase = Kg + (size_t)sr * KSTR + h * THD + sc;
    const ushort* vbase = Vg + (size_t)sr * KSTR + h * THD + sc;

    // ---- prologue: stage tile 0 into buf 0; prefetch tile 1 into regs ----
    uint4 kr0, kr1, vr0, vr1;
    kr0 = *(const uint4*)kbase;
    kr1 = *(const uint4*)(kbase + (size_t)32 * KSTR);
    vr0 = *(const uint4*)vbase;
    vr1 = *(const uint4*)(vbase + (size_t)32 * KSTR);
    {
        *(uint4*)swzK(&Ks[0][0], sr, sc * 2) = kr0;
        *(uint4*)swzK(&Ks[0][0], sr + 32, sc * 2) = kr1;
        const ushort* p0 = (const ushort*)&vr0;
        const ushort* p1 = (const ushort*)&vr1;
#pragma unroll
        for (int j = 0; j < 8; ++j) {
            *swzVT(&VTs[0][0], sc + j, sr * 2) = p0[j];
            *swzVT(&VTs[0][0], sc + j, (sr + 32) * 2) = p1[j];
        }
    }
    if (qb >= 1) {
        const size_t off = (size_t)64 * KSTR;
        kr0 = *(const uint4*)(kbase + off);
        kr1 = *(const uint4*)(kbase + off + (size_t)32 * KSTR);
        vr0 = *(const uint4*)(vbase + off);
        vr1 = *(const uint4*)(vbase + off + (size_t)32 * KSTR);
    }

    for (int kt = 0; kt <= qb; ++kt) {
        __syncthreads();   // tile kt staged; readers of buf[(kt+1)&1] done
        if (kt < qb) {
            // ---- stage tile kt+1 into the other buffer (overlaps compute) ----
            ushort* kd = &Ks[(kt + 1) & 1][0];
            ushort* vd = &VTs[(kt + 1) & 1][0];
            *(uint4*)swzK(kd, sr, sc * 2) = kr0;
            *(uint4*)swzK(kd, sr + 32, sc * 2) = kr1;
            const ushort* p0 = (const ushort*)&vr0;
            const ushort* p1 = (const ushort*)&vr1;
#pragma unroll
            for (int j = 0; j < 8; ++j) {
                *swzVT(vd, sc + j, sr * 2) = p0[j];
                *swzVT(vd, sc + j, (sr + 32) * 2) = p1[j];
            }
            if (kt + 1 < qb) {   // prefetch tile kt+2 into regs
                const size_t off = (size_t)(kt + 2) * 64 * KSTR;
                kr0 = *(const uint4*)(kbase + off);
                kr1 = *(const uint4*)(kbase + off + (size_t)32 * KSTR);
                vr0 = *(const uint4*)(vbase + off);
                vr1 = *(const uint4*)(vbase + off + (size_t)32 * KSTR);
            }
        }
        const ushort* kb_lds = &Ks[kt & 1][0];
        const ushort* vb_lds = &VTs[kt & 1][0];

        // ---- scores SWAPPED: s[nt][i] = rawscore[key = kt*64+nt*16+l4*4+i][q=l15]
        f32x4 s[4] = {};
        __builtin_amdgcn_s_setprio(1);
#pragma unroll
        for (int ks = 0; ks < 2; ++ks) {
#pragma unroll
            for (int nt = 0; nt < 4; ++nt) {
                const bf16x8 kf = *(const bf16x8*)swzK((ushort*)kb_lds, nt * 16 + l15, ks * 64 + l4 * 16);
                s[nt] = __builtin_amdgcn_mfma_f32_16x16x32_bf16(kf, qf[ks], s[nt], 0, 0, 0);
            }
        }
        __builtin_amdgcn_s_setprio(0);

        // ---- causal mask: ONLY the diagonal tile needs it (wave-uniform branch)
        if (kt == qb) {
            const int kb = kt * 64;
#pragma unroll
            for (int nt = 0; nt < 4; ++nt)
#pragma unroll
                for (int i = 0; i < 4; ++i)
                    if (kb + nt * 16 + l4 * 4 + i > myq) s[nt][i] = -3.0e38f;
        }

        // ---- per-lane softmax (raw domain; exp2 with folded scale) ----
        float mx = m_run;
#pragma unroll
        for (int nt = 0; nt < 4; ++nt)
#pragma unroll
            for (int i = 0; i < 4; ++i) mx = fmaxf(mx, s[nt][i]);
        mx = fmaxf(mx, __shfl_xor(mx, 16));
        mx = fmaxf(mx, __shfl_xor(mx, 32));
        const float alpha = exp2f((m_run - mx) * CE);
        m_run = mx;
        float ps = 0.f;
#pragma unroll
        for (int nt = 0; nt < 4; ++nt)
#pragma unroll
            for (int i = 0; i < 4; ++i) {
                const float p = exp2f((s[nt][i] - mx) * CE);
                s[nt][i] = p;
                ps += p;
            }
        ps += __shfl_xor(ps, 16);
        ps += __shfl_xor(ps, 32);
        l_run = l_run * alpha + ps;

        // ---- rescale oacc with OWN alpha (no broadcast needed) ----
#pragma unroll
        for (int dt = 0; dt < 4; ++dt)
#pragma unroll
            for (int i = 0; i < 4; ++i) oacc[dt][i] *= alpha;

        // ---- P -> LDS [q=l15][key], packed 4 keys per store (HW cvt pairs) ----
#pragma unroll
        for (int nt = 0; nt < 4; ++nt) {
            ushort4 pk;
            pk.x = f2bf_hw(s[nt][0]); pk.y = f2bf_hw(s[nt][1]);
            pk.z = f2bf_hw(s[nt][2]); pk.w = f2bf_hw(s[nt][3]);
            *(ushort4*)swzP(l15, nt * 32 + l4 * 8) = pk;
        }

        // ---- PV SWAPPED: oacc[dt] += mfma(V^T-frag, P-frag) -> o[d][q=l15] ----
        __builtin_amdgcn_s_setprio(1);
#pragma unroll
        for (int ks = 0; ks < 2; ++ks) {
            const bf16x8 pf = *(const bf16x8*)swzP(l15, ks * 64 + l4 * 16);
#pragma unroll
            for (int dt = 0; dt < 4; ++dt) {
                const bf16x8 vf = *(const bf16x8*)swzVT((ushort*)vb_lds, dt * 16 + l15, ks * 64 + l4 * 16);
                oacc[dt] = __builtin_amdgcn_mfma_f32_16x16x32_bf16(vf, pf, oacc[dt], 0, 0, 0);
            }
        }
        __builtin_amdgcn_s_setprio(0);
    }

    // ---- epilogue: lane owns row myq entirely; 4x ushort4 stores ----
    const float inv = 1.f / l_run;
#pragma unroll
    for (int dt = 0; dt < 4; ++dt) {
        ushort4 o4;
        o4.x = f2bf_hw(oacc[dt][0] * inv);
        o4.y = f2bf_hw(oacc[dt][1] * inv);
        o4.z = f2bf_hw(oacc[dt][2] * inv);
        o4.w = f2bf_hw(oacc[dt][3] * inv);
        *(ushort4*)&O[(size_t)myq * QSTR + h * THD + dt * 16 + l4 * 4] = o4;
    }
}

// ---------------- launch ----------------
extern "C" void kernel_launch(void* const* d_in, const int* in_sizes, int n_in,
                              void* d_out, int out_size, void* d_ws, size_t ws_size,
                              hipStream_t stream)
{
    const float* x     = (const float*)d_in[0];
    const float* g1    = (const float*)d_in[1];
    const float* Wq    = (const float*)d_in[2];
    const float* bq    = (const float*)d_in[3];
    const float* Wdown = (const float*)d_in[4];
    const float* bdown = (const float*)d_in[5];
    const float* Wk    = (const float*)d_in[6];
    const float* bk    = (const float*)d_in[7];
    const float* Wv    = (const float*)d_in[8];
    const float* bv    = (const float*)d_in[9];
    const float* Wo    = (const float*)d_in[10];
    const float* bo    = (const float*)d_in[11];
    const float* g2    = (const float*)d_in[12];
    const float* W1    = (const float*)d_in[13];
    const float* b1    = (const float*)d_in[14];
    const float* W2    = (const float*)d_in[15];
    const float* b2    = (const float*)d_in[16];
    float* out = (float*)d_out;

    char* ws = (char*)d_ws;
    size_t off = 0;
    auto alloc = [&](size_t bytes) {
        void* p = ws + off;
        off += (bytes + 255) & ~(size_t)255;
        return p;
    };
    ushort* WqT    = (ushort*)alloc((size_t)TH * TD * 2);
    ushort* WdownT = (ushort*)alloc((size_t)TL * TD * 2);
    ushort* WkvT   = (ushort*)alloc((size_t)2 * TH * TL * 2);  // [2048][256]
    ushort* WoT    = (ushort*)alloc((size_t)TD * TH * 2);
    ushort* W1T    = (ushort*)alloc((size_t)TDF * TD * 2);
    ushort* W2T    = (ushort*)alloc((size_t)TD * TDF * 2);
    float*  bkv    = (float*)alloc((size_t)2 * TH * 4);
    ushort* hbuf   = (ushort*)alloc((size_t)TS * TD * 2);
    ushort* cbuf   = (ushort*)alloc((size_t)TS * TL * 2);
    ushort* qbuf   = (ushort*)alloc((size_t)TS * TH * 2);
    ushort* kvbuf  = (ushort*)alloc((size_t)TS * 2 * TH * 2);  // [S][2048]
    ushort* obuf   = (ushort*)alloc((size_t)TS * TH * 2);
    float*  strm   = (float*)alloc((size_t)TS * TD * 4);
    ushort* h2buf  = (ushort*)alloc((size_t)TS * TD * 2);
    ushort* ffn1   = (ushort*)alloc((size_t)TS * TDF * 2);

    const dim3 tb(32, 8);
    transpose_to_bf16<<<dim3(TD / 32, TH / 32), tb, 0, stream>>>(Wq, WqT, TD, TH);
    transpose_to_bf16<<<dim3(TD / 32, TL / 32), tb, 0, stream>>>(Wdown, WdownT, TD, TL);
    transpose_to_bf16<<<dim3(TL / 32, TH / 32), tb, 0, stream>>>(Wk, WkvT, TL, TH);
    transpose_to_bf16<<<dim3(TL / 32, TH / 32), tb, 0, stream>>>(Wv, WkvT + (size_t)TH * TL, TL, TH);
    transpose_to_bf16<<<dim3(TH / 32, TD / 32), tb, 0, stream>>>(Wo, WoT, TH, TD);
    transpose_to_bf16<<<dim3(TD / 32, TDF / 32), tb, 0, stream>>>(W1, W1T, TD, TDF);
    transpose_to_bf16<<<dim3(TDF / 32, TD / 32), tb, 0, stream>>>(W2, W2T, TDF, TD);
    concat_bias_kernel<<<(2 * TH) / 256, 256, 0, stream>>>(bk, bv, bkv, TH);

    rmsnorm_kernel<<<TS, 256, 0, stream>>>(x, g1, hbuf, TD);

    gemm_bf16_kernel<0, 64, 64><<<dim3(TH / 64, TS / 64), 256, 0, stream>>>(
        hbuf, WqT, bq, nullptr, qbuf, TS, TH, TD);
    gemm_bf16_kernel<0, 64, 64><<<dim3(TL / 64, TS / 64), 256, 0, stream>>>(
        hbuf, WdownT, bdown, nullptr, cbuf, TS, TL, TD);
    gemm_bf16_kernel<0, 64, 64><<<dim3(2 * TH / 64, TS / 64), 256, 0, stream>>>(
        cbuf, WkvT, bkv, nullptr, kvbuf, TS, 2 * TH, TL);

    mla_attn_kernel<<<dim3(TS / 64, TNH), 256, 0, stream>>>(
        qbuf, kvbuf, kvbuf + TH, obuf);

    gemm_bf16_kernel<2, 64, 64><<<dim3(TD / 64, TS / 64), 256, 0, stream>>>(
        obuf, WoT, bo, x, strm, TS, TD, TH);

    rmsnorm_kernel<<<TS, 256, 0, stream>>>(strm, g2, h2buf, TD);

    gemm_bf16_kernel<1, 128, 128><<<dim3(TDF / 128, TS / 128), 256, 0, stream>>>(
        h2buf, W1T, b1, nullptr, ffn1, TS, TDF, TD);
    gemm_bf16_kernel<3, 64, 64><<<dim3(TD / 64, TS / 64), 256, 0, stream>>>(
        ffn1, W2T, b2, strm, out, TS, TD, TDF);
}

// Round 10
// 216.422 us; speedup vs baseline: 1.3558x; 1.0697x over previous
//
#include <hip/hip_runtime.h>

// ---------------- types ----------------
typedef __bf16 bf16x8 __attribute__((ext_vector_type(8)));
typedef float  f32x4  __attribute__((ext_vector_type(4)));

static __device__ __forceinline__ ushort f2bf(float f) {
    union { float f; unsigned u; } a; a.f = f;
    unsigned r = a.u + 0x7FFFu + ((a.u >> 16) & 1u);   // RNE
    return (ushort)(r >> 16);
}
static __device__ __forceinline__ ushort f2bf_hw(float f) {
    __bf16 b = (__bf16)f;                               // HW cvt (RNE), pairs -> cvt_pk
    return __builtin_bit_cast(ushort, b);
}

// ---------------- constants ----------------
#define TS  2048   // S
#define TD  1024   // D
#define TL  256    // L
#define TH  1024   // H
#define TNH 16
#define THD 64
#define TDF 4096   // 4*D
#define ATT_CE 0.18033688f   // 0.125 * log2(e)

#define GLD_LDS(gp, lp) \
    __builtin_amdgcn_global_load_lds( \
        (const __attribute__((address_space(1))) unsigned int*)(gp), \
        (__attribute__((address_space(3))) unsigned int*)(lp), 16, 0, 0)

// ---------------- weight transpose + f32->bf16 ----------------
__global__ __launch_bounds__(256) void transpose_to_bf16(
    const float* __restrict__ in, ushort* __restrict__ out, int K, int N)
{
    __shared__ float tile[32][33];
    const int k0 = blockIdx.x * 32, n0 = blockIdx.y * 32;
    const int tx = threadIdx.x, ty = threadIdx.y;   // block (32,8)
#pragma unroll
    for (int i = ty; i < 32; i += 8)
        tile[i][tx] = in[(size_t)(k0 + i) * N + n0 + tx];
    __syncthreads();
#pragma unroll
    for (int i = ty; i < 32; i += 8)
        out[(size_t)(n0 + i) * K + k0 + tx] = f2bf(tile[tx][i]);
}

// ---------------- small: concat two bias vectors ----------------
__global__ __launch_bounds__(256) void concat_bias_kernel(
    const float* __restrict__ a, const float* __restrict__ b,
    float* __restrict__ o, int n)
{
    const int i = blockIdx.x * 256 + threadIdx.x;
    o[i] = (i < n) ? a[i] : b[i - n];
}

// ---------------- RMSNorm: f32 in -> bf16 out ----------------
__global__ __launch_bounds__(256) void rmsnorm_kernel(
    const float* __restrict__ x, const float* __restrict__ g,
    ushort* __restrict__ out, int D)
{
    const int row = blockIdx.x;
    const int tid = threadIdx.x;
    const float4 v = ((const float4*)(x + (size_t)row * D))[tid];
    float ss = v.x * v.x + v.y * v.y + v.z * v.z + v.w * v.w;
#pragma unroll
    for (int off = 32; off > 0; off >>= 1) ss += __shfl_down(ss, off);
    __shared__ float sums[4];
    if ((tid & 63) == 0) sums[tid >> 6] = ss;
    __syncthreads();
    const float tot = sums[0] + sums[1] + sums[2] + sums[3];
    const float scale = rsqrtf(tot / (float)D + 1e-6f);
    const float4 gv = ((const float4*)g)[tid];
    ushort4 o;
    o.x = f2bf(v.x * scale * gv.x);
    o.y = f2bf(v.y * scale * gv.y);
    o.z = f2bf(v.z * scale * gv.z);
    o.w = f2bf(v.w * scale * gv.w);
    *(ushort4*)(out + (size_t)row * D + tid * 4) = o;
}

// ---------------- bf16 GEMM (2-phase): C = A @ BT^T + bias, epilogue --------
// BKH = number of 32-wide K half-tiles per step (effective BK = 32*BKH).
// BKH=2 halves barrier/drain count for small tiles; W1 keeps 128^2/BKH=1.
// EPI: 0=bf16; 1=silu->bf16; 2=+resid->f32; 3=silu+resid->f32
template <int EPI, int BM, int BN, int BKH>
__global__ __launch_bounds__(256) void gemm_bf16_kernel(
    const ushort* __restrict__ A, const ushort* __restrict__ BT,
    const float* __restrict__ bias, const float* __restrict__ resid,
    void* __restrict__ outp, int M, int N, int K)
{
    constexpr int WM = BM / 2, WN = BN / 2;
    constexpr int MT = WM / 16, NT = WN / 16;
    constexpr int NLA = BM / 64, NLB = BN / 64;
    __shared__ alignas(16) ushort As[2][BKH][BM * 32];
    __shared__ alignas(16) ushort Bs[2][BKH][BN * 32];
    const int bm = blockIdx.y * BM, bn = blockIdx.x * BN;
    const int tid = threadIdx.x;
    const int lane = tid & 63, wave = tid >> 6;
    const int wr = (wave >> 1) * WM, wc = (wave & 1) * WN;
    const int l15 = lane & 15, l4 = lane >> 4;

    f32x4 acc[MT][NT] = {};

    const int grow = wave * 16 + (lane >> 2);
    const int gcol = (lane & 3) * 8;
    const ushort* Ag = A + (size_t)(bm + grow) * K + gcol;
    const ushort* Bg = BT + (size_t)(bn + grow) * K + gcol;

    auto stage = [&](int buf, int k0) {
#pragma unroll
        for (int h = 0; h < BKH; ++h) {
#pragma unroll
            for (int i = 0; i < NLA; ++i)
                GLD_LDS(Ag + (size_t)(i * 64) * K + k0 + h * 32,
                        &As[buf][h][(i * 64 + wave * 16) * 32]);
#pragma unroll
            for (int i = 0; i < NLB; ++i)
                GLD_LDS(Bg + (size_t)(i * 64) * K + k0 + h * 32,
                        &Bs[buf][h][(i * 64 + wave * 16) * 32]);
        }
    };

    stage(0, 0);
    asm volatile("s_waitcnt vmcnt(0)" ::: "memory");
    __syncthreads();

    const int nsteps = K / (32 * BKH);
    for (int t = 0; t < nsteps; ++t) {
        const int cur = t & 1;
        if (t + 1 < nsteps) stage(cur ^ 1, (t + 1) * 32 * BKH);

#pragma unroll
        for (int h = 0; h < BKH; ++h) {
            bf16x8 af[MT], bf[NT];
#pragma unroll
            for (int mt = 0; mt < MT; ++mt)
                af[mt] = *(const bf16x8*)&As[cur][h][(wr + mt * 16 + l15) * 32 + l4 * 8];
#pragma unroll
            for (int nt = 0; nt < NT; ++nt)
                bf[nt] = *(const bf16x8*)&Bs[cur][h][(wc + nt * 16 + l15) * 32 + l4 * 8];
#pragma unroll
            for (int mt = 0; mt < MT; ++mt)
#pragma unroll
                for (int nt = 0; nt < NT; ++nt)
                    acc[mt][nt] = __builtin_amdgcn_mfma_f32_16x16x32_bf16(
                        af[mt], bf[nt], acc[mt][nt], 0, 0, 0);
        }

        asm volatile("s_waitcnt vmcnt(0)" ::: "memory");
        __syncthreads();
    }

#pragma unroll
    for (int mt = 0; mt < MT; ++mt) {
#pragma unroll
        for (int nt = 0; nt < NT; ++nt) {
#pragma unroll
            for (int i = 0; i < 4; ++i) {
                const int row = bm + wr + mt * 16 + l4 * 4 + i;
                const int col = bn + wc + nt * 16 + l15;
                float v = acc[mt][nt][i] + bias[col];
                if constexpr (EPI == 1 || EPI == 3) v = v / (1.f + __expf(-v));  // silu
                if constexpr (EPI == 2 || EPI == 3) v += resid[(size_t)row * N + col];
                if constexpr (EPI == 0 || EPI == 1)
                    ((ushort*)outp)[(size_t)row * N + col] = f2bf(v);
                else
                    ((float*)outp)[(size_t)row * N + col] = v;
            }
        }
    }
}

// ---------------- causal flash attention (MLA), split-KV x2 across blocks ----
// grid (S/64, NH, 2). Block (qb,h,sp) processes kv-tiles [kt0, ktend) of the
// causal range; writes UNNORMALIZED O-partial (f32) + per-row (m,l).
// Loop body = round-9 proven (swapped QK^T + swapped PV, per-lane softmax,
// dbuf K/V LDS, one barrier/tile). Blocks fully independent (no in-block
// split coupling -- that regressed in round 5).
__global__ __launch_bounds__(256) void mla_attn_kernel(
    const ushort* __restrict__ Q, const ushort* __restrict__ Kg,
    const ushort* __restrict__ Vg, float* __restrict__ OP, float* __restrict__ ML)
{
    constexpr int QSTR = 1024, KSTR = 2048;
    __shared__ alignas(16) ushort Ks[2][64 * 64];    // [buf][key][d], lo-swz
    __shared__ alignas(16) ushort VTs[2][64 * 64];   // [buf][d][key], hi-swz
    __shared__ alignas(16) ushort Ps[4][16 * 64];    // per-wave [q][key], lo-swz
    const int qb = (int)gridDim.x - 1 - (int)blockIdx.x;   // heavy blocks first
    const int h = blockIdx.y;
    const int sp = blockIdx.z;
    const int tid = threadIdx.x, lane = tid & 63, wave = tid >> 6;
    const int l15 = lane & 15, l4 = lane >> 4;
    const int qrow0 = qb * 64 + wave * 16;
    const int myq = qrow0 + l15;

    const int ntile = qb + 1;
    const int half = (ntile + 1) >> 1;
    const int kt0 = sp ? half : 0;
    const int ktend = sp ? ntile : half;

    auto swzK = [](ushort* base, int row, int colbyte) -> ushort* {
        return (ushort*)((char*)base + row * 128 + (colbyte ^ ((row & 7) << 4)));
    };
    auto swzVT = [](ushort* base, int d, int colbyte) -> ushort* {
        return (ushort*)((char*)base + d * 128 + (colbyte ^ (((d >> 3) & 7) << 4)));
    };
    auto swzP = [&](int row, int colbyte) -> ushort* {
        return (ushort*)((char*)&Ps[wave][0] + row * 128 + (colbyte ^ ((row & 7) << 4)));
    };

    bf16x8 qf[2];
#pragma unroll
    for (int ks = 0; ks < 2; ++ks)
        qf[ks] = *(const bf16x8*)&Q[(size_t)(qrow0 + l15) * QSTR + h * THD + ks * 32 + l4 * 8];

    f32x4 oacc[4] = {};          // oacc[dt][i] = o[d = dt*16 + l4*4 + i][q = myq]
    float m_run = -1e30f, l_run = 0.f;   // raw-score domain

    const int sr = tid >> 3, sc = (tid & 7) * 8;  // staging (32 rows x 64 cols)
    const ushort* kbase = Kg + (size_t)sr * KSTR + h * THD + sc;
    const ushort* vbase = Vg + (size_t)sr * KSTR + h * THD + sc;

    // ---- prologue: stage tile kt0 into buf 0; prefetch tile kt0+1 into regs ----
    uint4 kr0, kr1, vr0, vr1;
    {
        const size_t off = (size_t)kt0 * 64 * KSTR;
        kr0 = *(const uint4*)(kbase + off);
        kr1 = *(const uint4*)(kbase + off + (size_t)32 * KSTR);
        vr0 = *(const uint4*)(vbase + off);
        vr1 = *(const uint4*)(vbase + off + (size_t)32 * KSTR);
    }
    {
        *(uint4*)swzK(&Ks[0][0], sr, sc * 2) = kr0;
        *(uint4*)swzK(&Ks[0][0], sr + 32, sc * 2) = kr1;
        const ushort* p0 = (const ushort*)&vr0;
        const ushort* p1 = (const ushort*)&vr1;
#pragma unroll
        for (int j = 0; j < 8; ++j) {
            *swzVT(&VTs[0][0], sc + j, sr * 2) = p0[j];
            *swzVT(&VTs[0][0], sc + j, (sr + 32) * 2) = p1[j];
        }
    }
    if (kt0 + 1 < ktend) {
        const size_t off = (size_t)(kt0 + 1) * 64 * KSTR;
        kr0 = *(const uint4*)(kbase + off);
        kr1 = *(const uint4*)(kbase + off + (size_t)32 * KSTR);
        vr0 = *(const uint4*)(vbase + off);
        vr1 = *(const uint4*)(vbase + off + (size_t)32 * KSTR);
    }

    for (int kt = kt0; kt < ktend; ++kt) {
        const int rel = kt - kt0;
        __syncthreads();   // tile kt staged; readers of other buf done
        if (kt + 1 < ktend) {
            ushort* kd = &Ks[(rel + 1) & 1][0];
            ushort* vd = &VTs[(rel + 1) & 1][0];
            *(uint4*)swzK(kd, sr, sc * 2) = kr0;
            *(uint4*)swzK(kd, sr + 32, sc * 2) = kr1;
            const ushort* p0 = (const ushort*)&vr0;
            const ushort* p1 = (const ushort*)&vr1;
#pragma unroll
            for (int j = 0; j < 8; ++j) {
                *swzVT(vd, sc + j, sr * 2) = p0[j];
                *swzVT(vd, sc + j, (sr + 32) * 2) = p1[j];
            }
            if (kt + 2 < ktend) {
                const size_t off = (size_t)(kt + 2) * 64 * KSTR;
                kr0 = *(const uint4*)(kbase + off);
                kr1 = *(const uint4*)(kbase + off + (size_t)32 * KSTR);
                vr0 = *(const uint4*)(vbase + off);
                vr1 = *(const uint4*)(vbase + off + (size_t)32 * KSTR);
            }
        }
        const ushort* kb_lds = &Ks[rel & 1][0];
        const ushort* vb_lds = &VTs[rel & 1][0];

        // ---- scores SWAPPED: s[nt][i] = rawscore[key][q=l15] ----
        f32x4 s[4] = {};
        __builtin_amdgcn_s_setprio(1);
#pragma unroll
        for (int ks = 0; ks < 2; ++ks) {
#pragma unroll
            for (int nt = 0; nt < 4; ++nt) {
                const bf16x8 kf = *(const bf16x8*)swzK((ushort*)kb_lds, nt * 16 + l15, ks * 64 + l4 * 16);
                s[nt] = __builtin_amdgcn_mfma_f32_16x16x32_bf16(kf, qf[ks], s[nt], 0, 0, 0);
            }
        }
        __builtin_amdgcn_s_setprio(0);

        // ---- causal mask: only the diagonal tile ----
        if (kt == qb) {
            const int kb = kt * 64;
#pragma unroll
            for (int nt = 0; nt < 4; ++nt)
#pragma unroll
                for (int i = 0; i < 4; ++i)
                    if (kb + nt * 16 + l4 * 4 + i > myq) s[nt][i] = -3.0e38f;
        }

        // ---- per-lane softmax (raw domain; exp2 with folded scale) ----
        float mx = m_run;
#pragma unroll
        for (int nt = 0; nt < 4; ++nt)
#pragma unroll
            for (int i = 0; i < 4; ++i) mx = fmaxf(mx, s[nt][i]);
        mx = fmaxf(mx, __shfl_xor(mx, 16));
        mx = fmaxf(mx, __shfl_xor(mx, 32));
        const float alpha = exp2f((m_run - mx) * ATT_CE);
        m_run = mx;
        float ps = 0.f;
#pragma unroll
        for (int nt = 0; nt < 4; ++nt)
#pragma unroll
            for (int i = 0; i < 4; ++i) {
                const float p = exp2f((s[nt][i] - mx) * ATT_CE);
                s[nt][i] = p;
                ps += p;
            }
        ps += __shfl_xor(ps, 16);
        ps += __shfl_xor(ps, 32);
        l_run = l_run * alpha + ps;

#pragma unroll
        for (int dt = 0; dt < 4; ++dt)
#pragma unroll
            for (int i = 0; i < 4; ++i) oacc[dt][i] *= alpha;

        // ---- P -> LDS [q=l15][key], packed 4 keys per store ----
#pragma unroll
        for (int nt = 0; nt < 4; ++nt) {
            ushort4 pk;
            pk.x = f2bf_hw(s[nt][0]); pk.y = f2bf_hw(s[nt][1]);
            pk.z = f2bf_hw(s[nt][2]); pk.w = f2bf_hw(s[nt][3]);
            *(ushort4*)swzP(l15, nt * 32 + l4 * 8) = pk;
        }

        // ---- PV SWAPPED: oacc[dt] += mfma(V^T-frag, P-frag) -> o[d][q=l15] ----
        __builtin_amdgcn_s_setprio(1);
#pragma unroll
        for (int ks = 0; ks < 2; ++ks) {
            const bf16x8 pf = *(const bf16x8*)swzP(l15, ks * 64 + l4 * 16);
#pragma unroll
            for (int dt = 0; dt < 4; ++dt) {
                const bf16x8 vf = *(const bf16x8*)swzVT((ushort*)vb_lds, dt * 16 + l15, ks * 64 + l4 * 16);
                oacc[dt] = __builtin_amdgcn_mfma_f32_16x16x32_bf16(vf, pf, oacc[dt], 0, 0, 0);
            }
        }
        __builtin_amdgcn_s_setprio(0);
    }

    // ---- epilogue: write UNNORMALIZED partial + (m,l) ----
    float* op = OP + (size_t)sp * TS * TH;
#pragma unroll
    for (int dt = 0; dt < 4; ++dt) {
        float4 o4;
        o4.x = oacc[dt][0]; o4.y = oacc[dt][1];
        o4.z = oacc[dt][2]; o4.w = oacc[dt][3];
        *(float4*)&op[(size_t)myq * TH + h * THD + dt * 16 + l4 * 4] = o4;
    }
    if (l4 == 0) {   // lanes sharing l15 hold identical (m,l) after the reduces
        float* ml = ML + (size_t)sp * TS * TNH * 2;
        ml[((size_t)myq * TNH + h) * 2 + 0] = m_run;
        ml[((size_t)myq * TNH + h) * 2 + 1] = l_run;
    }
}

// ---------------- flash combine of the two KV-split partials ----------------
__global__ __launch_bounds__(256) void attn_combine_kernel(
    const float* __restrict__ OP, const float* __restrict__ ML,
    ushort* __restrict__ O)
{
    const int idx = blockIdx.x * 256 + threadIdx.x;   // one float4 of one row
    const int row = idx >> 8;                         // 256 float4 per row
    const int h = (idx & 255) >> 4;                   // 16 float4 per head
    const float m0 = ML[((size_t)row * TNH + h) * 2 + 0];
    const float l0 = ML[((size_t)row * TNH + h) * 2 + 1];
    const float m1 = ML[(size_t)TS * TNH * 2 + ((size_t)row * TNH + h) * 2 + 0];
    const float l1 = ML[(size_t)TS * TNH * 2 + ((size_t)row * TNH + h) * 2 + 1];
    const float M = fmaxf(m0, m1);
    const float w0 = exp2f((m0 - M) * ATT_CE);
    const float w1 = exp2f((m1 - M) * ATT_CE);
    const float inv = 1.f / (l0 * w0 + l1 * w1);
    const float4 a = ((const float4*)OP)[idx];
    const float4 b = ((const float4*)(OP + (size_t)TS * TH))[idx];
    ushort4 o;
    o.x = f2bf_hw((a.x * w0 + b.x * w1) * inv);
    o.y = f2bf_hw((a.y * w0 + b.y * w1) * inv);
    o.z = f2bf_hw((a.z * w0 + b.z * w1) * inv);
    o.w = f2bf_hw((a.w * w0 + b.w * w1) * inv);
    ((ushort4*)O)[idx] = o;
}

// ---------------- launch ----------------
extern "C" void kernel_launch(void* const* d_in, const int* in_sizes, int n_in,
                              void* d_out, int out_size, void* d_ws, size_t ws_size,
                              hipStream_t stream)
{
    const float* x     = (const float*)d_in[0];
    const float* g1    = (const float*)d_in[1];
    const float* Wq    = (const float*)d_in[2];
    const float* bq    = (const float*)d_in[3];
    const float* Wdown = (const float*)d_in[4];
    const float* bdown = (const float*)d_in[5];
    const float* Wk    = (const float*)d_in[6];
    const float* bk    = (const float*)d_in[7];
    const float* Wv    = (const float*)d_in[8];
    const float* bv    = (const float*)d_in[9];
    const float* Wo    = (const float*)d_in[10];
    const float* bo    = (const float*)d_in[11];
    const float* g2    = (const float*)d_in[12];
    const float* W1    = (const float*)d_in[13];
    const float* b1    = (const float*)d_in[14];
    const float* W2    = (const float*)d_in[15];
    const float* b2    = (const float*)d_in[16];
    float* out = (float*)d_out;

    char* ws = (char*)d_ws;
    size_t off = 0;
    auto alloc = [&](size_t bytes) {
        void* p = ws + off;
        off += (bytes + 255) & ~(size_t)255;
        return p;
    };
    ushort* WqT    = (ushort*)alloc((size_t)TH * TD * 2);
    ushort* WdownT = (ushort*)alloc((size_t)TL * TD * 2);
    ushort* WkvT   = (ushort*)alloc((size_t)2 * TH * TL * 2);  // [2048][256]
    ushort* WoT    = (ushort*)alloc((size_t)TD * TH * 2);
    ushort* W1T    = (ushort*)alloc((size_t)TDF * TD * 2);
    ushort* W2T    = (ushort*)alloc((size_t)TD * TDF * 2);
    float*  bkv    = (float*)alloc((size_t)2 * TH * 4);
    ushort* hbuf   = (ushort*)alloc((size_t)TS * TD * 2);
    ushort* cbuf   = (ushort*)alloc((size_t)TS * TL * 2);
    ushort* qbuf   = (ushort*)alloc((size_t)TS * TH * 2);
    ushort* kvbuf  = (ushort*)alloc((size_t)TS * 2 * TH * 2);  // [S][2048]
    ushort* obuf   = (ushort*)alloc((size_t)TS * TH * 2);
    float*  strm   = (float*)alloc((size_t)TS * TD * 4);
    ushort* h2buf  = (ushort*)alloc((size_t)TS * TD * 2);
    ushort* ffn1   = (ushort*)alloc((size_t)TS * TDF * 2);     // 16 MB
    float*  mlbuf  = (float*)alloc((size_t)2 * TS * TNH * 2 * 4);
    // O-partials (2 x S x H f32 = 16 MB) alias ffn1: dead until W1 runs.
    float*  opart  = (float*)ffn1;

    const dim3 tb(32, 8);
    transpose_to_bf16<<<dim3(TD / 32, TH / 32), tb, 0, stream>>>(Wq, WqT, TD, TH);
    transpose_to_bf16<<<dim3(TD / 32, TL / 32), tb, 0, stream>>>(Wdown, WdownT, TD, TL);
    transpose_to_bf16<<<dim3(TL / 32, TH / 32), tb, 0, stream>>>(Wk, WkvT, TL, TH);
    transpose_to_bf16<<<dim3(TL / 32, TH / 32), tb, 0, stream>>>(Wv, WkvT + (size_t)TH * TL, TL, TH);
    transpose_to_bf16<<<dim3(TH / 32, TD / 32), tb, 0, stream>>>(Wo, WoT, TH, TD);
    transpose_to_bf16<<<dim3(TD / 32, TDF / 32), tb, 0, stream>>>(W1, W1T, TD, TDF);
    transpose_to_bf16<<<dim3(TDF / 32, TD / 32), tb, 0, stream>>>(W2, W2T, TDF, TD);
    concat_bias_kernel<<<(2 * TH) / 256, 256, 0, stream>>>(bk, bv, bkv, TH);

    rmsnorm_kernel<<<TS, 256, 0, stream>>>(x, g1, hbuf, TD);

    gemm_bf16_kernel<0, 64, 64, 2><<<dim3(TH / 64, TS / 64), 256, 0, stream>>>(
        hbuf, WqT, bq, nullptr, qbuf, TS, TH, TD);
    gemm_bf16_kernel<0, 64, 64, 2><<<dim3(TL / 64, TS / 64), 256, 0, stream>>>(
        hbuf, WdownT, bdown, nullptr, cbuf, TS, TL, TD);
    gemm_bf16_kernel<0, 64, 64, 2><<<dim3(2 * TH / 64, TS / 64), 256, 0, stream>>>(
        cbuf, WkvT, bkv, nullptr, kvbuf, TS, 2 * TH, TL);

    mla_attn_kernel<<<dim3(TS / 64, TNH, 2), 256, 0, stream>>>(
        qbuf, kvbuf, kvbuf + TH, opart, mlbuf);
    attn_combine_kernel<<<(TS * TH / 4) / 256, 256, 0, stream>>>(
        opart, mlbuf, obuf);

    gemm_bf16_kernel<2, 64, 64, 2><<<dim3(TD / 64, TS / 64), 256, 0, stream>>>(
        obuf, WoT, bo, x, strm, TS, TD, TH);

    rmsnorm_kernel<<<TS, 256, 0, stream>>>(strm, g2, h2buf, TD);

    gemm_bf16_kernel<1, 128, 128, 1><<<dim3(TDF / 128, TS / 128), 256, 0, stream>>>(
        h2buf, W1T, b1, nullptr, ffn1, TS, TDF, TD);
    gemm_bf16_kernel<3, 64, 64, 2><<<dim3(TD / 64, TS / 64), 256, 0, stream>>>(
        ffn1, W2T, b2, strm, out, TS, TD, TDF);
}